// Round 1
// baseline (1355.343 us; speedup 1.0000x reference)
//
#include <hip/hip_runtime.h>
#include <hip/hip_bf16.h>
#include <math.h>

// Problem constants (fixed by reference)
#define NB 4
#define NR 4096
#define NC 32
#define NH 256
#define NW 256
#define NS 48
#define NRAYS (NB*NR)          // 16384
#define NSAMP (NRAYS*NS)       // 786432

__device__ __forceinline__ float coarse_depth(int i) {
    const float DELTA = 1.05f / 47.f;
    return 2.25f + i * DELTA + 0.5f * DELTA;
}
__device__ __forceinline__ float zmid_c(int i) {
    return 0.5f * (coarse_depth(i) + coarse_depth(i + 1));
}
__device__ __forceinline__ float softplus_f(float x) {
    // jax.nn.softplus: max(x,0) + log1p(exp(-|x|)) (stable)
    return fmaxf(x, 0.f) + log1pf(expf(-fabsf(x)));
}
__device__ __forceinline__ float sigmoid_f(float x) {
    return 1.f / (1.f + expf(-x));
}

// ---------------------------------------------------------------------------
// K0: transpose planes (B,3,C,H,W) -> channel-interleaved (B*3, H*W, C)
// so one sample tap = 32 contiguous floats (128B line).
// ---------------------------------------------------------------------------
__global__ __launch_bounds__(256) void k_transpose(const float* __restrict__ in,
                                                   float* __restrict__ out) {
    __shared__ float tile[32][65];
    int bp = blockIdx.x >> 10;            // 0..11  (b*3+p)
    int t0 = (blockIdx.x & 1023) * 64;    // pixel base within 65536
    const float* src = in + (size_t)bp * NC * NH * NW;
    float* dst = out + (size_t)bp * NH * NW * NC;
    int px = threadIdx.x & 63;
    int c0 = threadIdx.x >> 6;            // 0..3
    #pragma unroll
    for (int cc = 0; cc < 32; cc += 4)
        tile[cc + c0][px] = src[(size_t)(cc + c0) * NH * NW + t0 + px];
    __syncthreads();
    int c = threadIdx.x & 31;
    int p0 = threadIdx.x >> 5;            // 0..7
    #pragma unroll
    for (int pp = 0; pp < 64; pp += 8)
        dst[(size_t)(t0 + pp + p0) * NC + c] = tile[c][pp + p0];
}

// Bilinear tap with zero-padding semantics matching the reference gather
__device__ __forceinline__ float tapv(const float* __restrict__ base,
                                      int xi, int yi, int c) {
    bool valid = (xi >= 0) & (xi < NW) & (yi >= 0) & (yi < NH);
    int xc = min(max(xi, 0), NW - 1);
    int yc = min(max(yi, 0), NH - 1);
    float v = base[((size_t)yc * NW + xc) * NC + c];
    return valid ? v : 0.f;
}

// ---------------------------------------------------------------------------
// K1/K3: sample tri-planes + decode MLP. Half-wave (32 lanes, lane=channel)
// per sample for coalesced taps; then thread-per-sample MLP from LDS.
// ---------------------------------------------------------------------------
template<bool FINE>
__global__ __launch_bounds__(256) void k_sample_decode(
    const float* __restrict__ planes_t,
    const float* __restrict__ origins,
    const float* __restrict__ dirs,
    const float* __restrict__ dfine,       // null for coarse
    const float* __restrict__ w1, const float* __restrict__ b1,
    const float* __restrict__ w2, const float* __restrict__ b2,
    float* __restrict__ rgb_out, float* __restrict__ sig_out)
{
    __shared__ float xbuf[256][33];   // +1 pad: kills 64-way bank conflict
    __shared__ float w1s[2048];
    __shared__ float w2s[2112];
    __shared__ float b1s[64];
    __shared__ float b2s[33];
    for (int i = threadIdx.x; i < 2048; i += 256) w1s[i] = w1[i];
    for (int i = threadIdx.x; i < 2112; i += 256) w2s[i] = w2[i];
    if (threadIdx.x < 64) b1s[threadIdx.x] = b1[threadIdx.x];
    if (threadIdx.x < 33) b2s[threadIdx.x] = b2[threadIdx.x];
    __syncthreads();

    int lane = threadIdx.x & 31;
    int hw = threadIdx.x >> 5;        // 0..7 half-wave id

    #pragma unroll 1
    for (int it = 0; it < 32; ++it) {
        int ls = it * 8 + hw;                 // local sample 0..255
        int s = blockIdx.x * 256 + ls;        // global sample
        int ray = s / NS;
        int k = s - ray * NS;
        float t = FINE ? dfine[s] : coarse_depth(k);
        float ox = origins[ray*3+0], oy = origins[ray*3+1], oz = origins[ray*3+2];
        float ddx = dirs[ray*3+0],   ddy = dirs[ray*3+1],   ddz = dirs[ray*3+2];
        float cx = 2.f * (ox + t * ddx);
        float cy = 2.f * (oy + t * ddy);
        float cz = 2.f * (oz + t * ddz);
        int bi = ray >> 12;                   // /NR
        float acc = 0.f;
        #pragma unroll
        for (int p = 0; p < 3; ++p) {
            // plane0:(cx,cy)  plane1:(cx,cz)  plane2:(cz,cx)
            float gx = (p == 2) ? cz : cx;
            float gy = (p == 0) ? cy : ((p == 1) ? cz : cx);
            float fx = (gx + 1.f) * 128.f - 0.5f;
            float fy = (gy + 1.f) * 128.f - 0.5f;
            float x0f = floorf(fx), y0f = floorf(fy);
            float wx = fx - x0f, wy = fy - y0f;
            int x0 = (int)x0f, y0 = (int)y0f;
            const float* base = planes_t + (size_t)(bi * 3 + p) * NH * NW * NC;
            float v00 = tapv(base, x0,     y0,     lane);
            float v10 = tapv(base, x0 + 1, y0,     lane);
            float v01 = tapv(base, x0,     y0 + 1, lane);
            float v11 = tapv(base, x0 + 1, y0 + 1, lane);
            acc += v00*(1.f-wx)*(1.f-wy) + v10*wx*(1.f-wy)
                 + v01*(1.f-wx)*wy       + v11*wx*wy;
        }
        xbuf[ls][lane] = acc / 3.f;   // mean over 3 planes
    }
    __syncthreads();

    // MLP: thread-per-sample
    float x[32];
    #pragma unroll
    for (int c = 0; c < 32; ++c) x[c] = xbuf[threadIdx.x][c];
    float o[33];
    #pragma unroll
    for (int k2 = 0; k2 < 33; ++k2) o[k2] = b2s[k2];
    #pragma unroll 1
    for (int j = 0; j < 64; ++j) {
        float a = b1s[j];
        #pragma unroll
        for (int c = 0; c < 32; ++c) a += x[c] * w1s[c * 64 + j];
        float h = softplus_f(a);
        #pragma unroll
        for (int k2 = 0; k2 < 33; ++k2) o[k2] += h * w2s[j * 33 + k2];
    }
    int sg = blockIdx.x * 256 + threadIdx.x;
    sig_out[sg] = o[0];
    #pragma unroll
    for (int c = 0; c < 32; ++c)
        xbuf[threadIdx.x][c] = sigmoid_f(o[1 + c]) * 1.002f - 0.001f;
    __syncthreads();
    // coalesced rgb write (half-wave, lane=channel)
    #pragma unroll 1
    for (int it = 0; it < 32; ++it) {
        int ls = it * 8 + hw;
        rgb_out[(size_t)(blockIdx.x * 256 + ls) * 32 + lane] = xbuf[ls][lane];
    }
}

// ---------------------------------------------------------------------------
// K2: coarse ray-march -> weights -> blur -> PDF -> 48 importance depths.
// Thread-per-ray, fully unrolled register arrays.
// ---------------------------------------------------------------------------
__global__ __launch_bounds__(256) void k_importance(const float* __restrict__ sig,
                                                    float* __restrict__ dfine) {
    int ray = blockIdx.x * 256 + threadIdx.x;
    const float* sp = sig + (size_t)ray * NS;
    float w[47];
    float T = 1.f;
    float sprev = sp[0];
    #pragma unroll
    for (int i = 0; i < 47; ++i) {
        float scur = sp[i + 1];
        float dens = softplus_f(0.5f * (sprev + scur) - 1.f);
        float delta = coarse_depth(i + 1) - coarse_depth(i);
        float alpha = 1.f - expf(-dens * delta);
        w[i] = alpha * T + 0.01f;            // weights + 0.01
        T *= (1.f - alpha + 1e-10f);
        sprev = scur;
    }
    // blur: wp=[-inf,w,-inf]; nw_i=max(wp_i,wp_{i+1}); wb=0.5*(nw_i+nw_{i+1})+0.01
    // pdf over wb[1..45] (+1e-5 eps)
    float p[45];
    float sum = 0.f;
    #pragma unroll
    for (int i = 1; i <= 45; ++i) {
        float nwi  = fmaxf(w[i - 1], w[i]);
        float nwi1 = fmaxf(w[i], w[i + 1]);
        float wb = 0.5f * (nwi + nwi1) + 0.01f;
        float v = wb + 1e-5f;
        p[i - 1] = v;
        sum += v;
    }
    // walk cdf against monotone u=(k+0.5)/48, searchsorted-right semantics
    int k = 0;
    float cdf_lo = 0.f;
    #pragma unroll
    for (int i = 0; i < 45; ++i) {
        float cdf_hi = cdf_lo + p[i] / sum;
        float bb = zmid_c(i), ba = zmid_c(i + 1);
        float denom = cdf_hi - cdf_lo;
        if (denom < 1e-5f) denom = 1.f;
        while (k < 48) {
            float u = (k + 0.5f) / 48.f;
            if (u < cdf_hi) {
                dfine[(size_t)ray * NS + k] = bb + (u - cdf_lo) / denom * (ba - bb);
                ++k;
            } else break;
        }
        cdf_lo = cdf_hi;
    }
    while (k < 48) {  // u >= cdf[last]: inds clamps, below==above -> bins[45]
        dfine[(size_t)ray * NS + k] = zmid_c(45);
        ++k;
    }
}

// ---------------------------------------------------------------------------
// K4: merge coarse+fine (stable-sort-equivalent ranks), background MLP,
// final ray-march. One wave per ray, lane&31 = channel.
// ---------------------------------------------------------------------------
__global__ __launch_bounds__(256) void k_final(
    const float* __restrict__ sig_c, const float* __restrict__ rgb_c,
    const float* __restrict__ sig_f, const float* __restrict__ rgb_f,
    const float* __restrict__ dfine,
    const float* __restrict__ dirs, const float* __restrict__ z_bg,
    const float* __restrict__ bw1, const float* __restrict__ bb1,
    const float* __restrict__ bw2, const float* __restrict__ bb2,
    float* __restrict__ out_rgb, float* __restrict__ out_dep,
    float* __restrict__ out_wt)
{
    __shared__ float s_d[4][96];
    __shared__ float s_sig[4][96];
    __shared__ int   s_src[4][96];
    __shared__ float s_fine[4][48];
    __shared__ float s_h[4][64];
    __shared__ float s_zb[64];
    int lane = threadIdx.x & 63;
    int wv = threadIdx.x >> 6;
    int ray = blockIdx.x * 4 + wv;
    int bi = (blockIdx.x * 4) >> 12;      // same b for all 4 rays in block
    if (threadIdx.x < 64) s_zb[threadIdx.x] = z_bg[bi * 64 + threadIdx.x];
    if (lane < 48) s_fine[wv][lane] = dfine[(size_t)ray * NS + lane];
    __syncthreads();

    if (lane < 48) {
        // coarse element rank = lane + #{fine < coarse}
        float cd = coarse_depth(lane);
        int lo = 0, hi = 48;
        while (lo < hi) { int mid = (lo + hi) >> 1;
            if (s_fine[wv][mid] < cd) lo = mid + 1; else hi = mid; }
        int rc = lane + lo;
        s_d[wv][rc] = cd;
        s_sig[wv][rc] = sig_c[(size_t)ray * NS + lane];
        s_src[wv][rc] = lane;
        // fine element rank = lane + #{coarse <= fine}
        float f = s_fine[wv][lane];
        lo = 0; hi = 48;
        while (lo < hi) { int mid = (lo + hi) >> 1;
            if (coarse_depth(mid) <= f) lo = mid + 1; else hi = mid; }
        int rf = lane + lo;
        s_d[wv][rf] = f;
        s_sig[wv][rf] = sig_f[(size_t)ray * NS + lane];
        s_src[wv][rf] = 48 + lane;
    }
    float ddx = dirs[ray*3+0], ddy = dirs[ray*3+1], ddz = dirs[ray*3+2];
    __syncthreads();

    // background MLP: lane j computes h_j (67->64), then lanes compute o_c (64->32)
    float a = bb1[lane] + ddx * bw1[lane] + ddy * bw1[64 + lane] + ddz * bw1[128 + lane];
    #pragma unroll 1
    for (int i = 0; i < 64; ++i) a += s_zb[i] * bw1[(3 + i) * 64 + lane];
    s_h[wv][lane] = softplus_f(a);
    __syncthreads();
    int c = lane & 31;
    float ob = bb2[c];
    #pragma unroll 1
    for (int j = 0; j < 64; ++j) ob += s_h[wv][j] * bw2[j * 32 + c];
    float bgc = sigmoid_f(ob);

    // final march over 96 merged samples
    size_t rbase = (size_t)ray * NS * 32;
    int src0 = s_src[wv][0];
    const float* cp0 = (src0 < 48) ? (rgb_c + rbase + (size_t)src0 * 32)
                                   : (rgb_f + rbase + (size_t)(src0 - 48) * 32);
    float prevc = cp0[c];
    float prevd = s_d[wv][0], prevs = s_sig[wv][0];
    float T = 1.f, crgb = 0.f, cdep = 0.f, wtot = 0.f;
    for (int i = 1; i < 96; ++i) {
        float di = s_d[wv][i], si = s_sig[wv][i];
        int srci = s_src[wv][i];
        const float* cpi = (srci < 48) ? (rgb_c + rbase + (size_t)srci * 32)
                                       : (rgb_f + rbase + (size_t)(srci - 48) * 32);
        float ci = cpi[c];
        float delta = di - prevd;
        float dens = softplus_f(0.5f * (prevs + si) - 1.f);
        float alpha = 1.f - expf(-dens * delta);
        float wt = alpha * T;
        T *= (1.f - alpha + 1e-10f);
        crgb += wt * 0.5f * (prevc + ci);
        cdep += wt * 0.5f * (prevd + di);
        wtot += wt;
        prevd = di; prevs = si; prevc = ci;
    }
    float rgbv = (crgb + T * bgc) * 2.f - 1.f;
    float dep = cdep / wtot;
    if (!(dep == dep)) dep = INFINITY;          // nan_to_num(nan -> inf)
    dep = fminf(fmaxf(dep, coarse_depth(0)), coarse_depth(47));
    if (lane < 32) out_rgb[(size_t)ray * 32 + c] = rgbv;
    if (lane == 0) { out_dep[ray] = dep; out_wt[ray] = wtot; }
}

// ---------------------------------------------------------------------------
extern "C" void kernel_launch(void* const* d_in, const int* in_sizes, int n_in,
                              void* d_out, int out_size, void* d_ws, size_t ws_size,
                              hipStream_t stream) {
    (void)in_sizes; (void)n_in; (void)out_size; (void)ws_size;
    const float* planes  = (const float*)d_in[0];
    const float* origins = (const float*)d_in[1];
    const float* dirs    = (const float*)d_in[2];
    const float* z_bg    = (const float*)d_in[3];
    const float* dw1     = (const float*)d_in[4];
    const float* db1     = (const float*)d_in[5];
    const float* dw2     = (const float*)d_in[6];
    const float* db2     = (const float*)d_in[7];
    const float* bw1     = (const float*)d_in[8];
    const float* bb1     = (const float*)d_in[9];
    const float* bw2     = (const float*)d_in[10];
    const float* bb2     = (const float*)d_in[11];

    // workspace layout (f32): total ~297 MiB
    char* ws = (char*)d_ws;
    size_t off = 0;
    float* planes_t = (float*)(ws + off); off += (size_t)NB * 3 * NH * NW * NC * 4;
    float* rgb_c    = (float*)(ws + off); off += (size_t)NSAMP * 32 * 4;
    float* rgb_f    = (float*)(ws + off); off += (size_t)NSAMP * 32 * 4;
    float* sig_c    = (float*)(ws + off); off += (size_t)NSAMP * 4;
    float* sig_f    = (float*)(ws + off); off += (size_t)NSAMP * 4;
    float* dfine    = (float*)(ws + off); off += (size_t)NSAMP * 4;

    float* out_rgb = (float*)d_out;
    float* out_dep = out_rgb + (size_t)NRAYS * 32;
    float* out_wt  = out_dep + NRAYS;

    k_transpose<<<dim3(NB * 3 * 1024), dim3(256), 0, stream>>>(planes, planes_t);
    k_sample_decode<false><<<dim3(NSAMP / 256), dim3(256), 0, stream>>>(
        planes_t, origins, dirs, (const float*)nullptr,
        dw1, db1, dw2, db2, rgb_c, sig_c);
    k_importance<<<dim3(NRAYS / 256), dim3(256), 0, stream>>>(sig_c, dfine);
    k_sample_decode<true><<<dim3(NSAMP / 256), dim3(256), 0, stream>>>(
        planes_t, origins, dirs, dfine,
        dw1, db1, dw2, db2, rgb_f, sig_f);
    k_final<<<dim3(NRAYS / 4), dim3(256), 0, stream>>>(
        sig_c, rgb_c, sig_f, rgb_f, dfine, dirs, z_bg,
        bw1, bb1, bw2, bb2, out_rgb, out_dep, out_wt);
}

// Round 3
// 905.748 us; speedup vs baseline: 1.4964x; 1.4964x over previous
//
#include <hip/hip_runtime.h>
#include <hip/hip_bf16.h>
#include <math.h>

// Problem constants (fixed by reference)
#define NB 4
#define NR 4096
#define NC 32
#define NH 256
#define NW 256
#define NS 48
#define NRAYS (NB*NR)          // 16384
#define NSAMP (NRAYS*NS)       // 786432

__device__ __forceinline__ float coarse_depth(int i) {
    const float DELTA = 1.05f / 47.f;
    return 2.25f + i * DELTA + 0.5f * DELTA;
}
__device__ __forceinline__ float zmid_c(int i) {
    return 0.5f * (coarse_depth(i) + coarse_depth(i + 1));
}
// fast softplus: max(x,0) + log(1+exp(-|x|)) via v_exp_f32/v_log_f32
__device__ __forceinline__ float softplus_f(float x) {
    return fmaxf(x, 0.f) + __logf(1.f + __expf(-fabsf(x)));
}
__device__ __forceinline__ float sigmoid_f(float x) {
    return __frcp_rn(1.f + __expf(-x));
}

// ---------------------------------------------------------------------------
// K0: transpose planes (B,3,C,H,W) -> channel-interleaved (B*3, H*W, C)
// so one sample tap = 32 contiguous floats (128B line).
// ---------------------------------------------------------------------------
__global__ __launch_bounds__(256) void k_transpose(const float* __restrict__ in,
                                                   float* __restrict__ out) {
    __shared__ float tile[32][65];
    int bp = blockIdx.x >> 10;            // 0..11  (b*3+p)
    int t0 = (blockIdx.x & 1023) * 64;    // pixel base within 65536
    const float* src = in + (size_t)bp * NC * NH * NW;
    float* dst = out + (size_t)bp * NH * NW * NC;
    int px = threadIdx.x & 63;
    int c0 = threadIdx.x >> 6;            // 0..3
    #pragma unroll
    for (int cc = 0; cc < 32; cc += 4)
        tile[cc + c0][px] = src[(size_t)(cc + c0) * NH * NW + t0 + px];
    __syncthreads();
    int c = threadIdx.x & 31;
    int p0 = threadIdx.x >> 5;            // 0..7
    #pragma unroll
    for (int pp = 0; pp < 64; pp += 8)
        dst[(size_t)(t0 + pp + p0) * NC + c] = tile[c][pp + p0];
}

// Bilinear tap with zero-padding semantics matching the reference gather
__device__ __forceinline__ float tapv(const float* __restrict__ base,
                                      int xi, int yi, int c) {
    bool valid = (xi >= 0) & (xi < NW) & (yi >= 0) & (yi < NH);
    int xc = min(max(xi, 0), NW - 1);
    int yc = min(max(yi, 0), NH - 1);
    float v = base[((size_t)yc * NW + xc) * NC + c];
    return valid ? v : 0.f;
}

// ---------------------------------------------------------------------------
// K1/K3: sample tri-planes + decode MLP. Half-wave (32 lanes, lane=channel)
// per sample for coalesced taps; then thread-per-sample MLP from LDS.
// ---------------------------------------------------------------------------
template<bool FINE>
__global__ __launch_bounds__(256) void k_sample_decode(
    const float* __restrict__ planes_t,
    const float* __restrict__ origins,
    const float* __restrict__ dirs,
    const float* __restrict__ dfine,       // null for coarse
    const float* __restrict__ w1, const float* __restrict__ b1,
    const float* __restrict__ w2, const float* __restrict__ b2,
    float* __restrict__ rgb_out, float* __restrict__ sig_out)
{
    __shared__ float xbuf[256][33];   // +1 pad: kills 64-way bank conflict
    __shared__ float w1s[2048];
    __shared__ float w2s[2112];
    __shared__ float b1s[64];
    __shared__ float b2s[33];
    for (int i = threadIdx.x; i < 2048; i += 256) w1s[i] = w1[i];
    for (int i = threadIdx.x; i < 2112; i += 256) w2s[i] = w2[i];
    if (threadIdx.x < 64) b1s[threadIdx.x] = b1[threadIdx.x];
    if (threadIdx.x < 33) b2s[threadIdx.x] = b2[threadIdx.x];
    __syncthreads();

    int lane = threadIdx.x & 31;
    int hw = threadIdx.x >> 5;        // 0..7 half-wave id

    #pragma unroll 1
    for (int it = 0; it < 32; ++it) {
        int ls = it * 8 + hw;                 // local sample 0..255
        int s = blockIdx.x * 256 + ls;        // global sample
        int ray = s / NS;
        int k = s - ray * NS;
        float t = FINE ? dfine[s] : coarse_depth(k);
        float ox = origins[ray*3+0], oy = origins[ray*3+1], oz = origins[ray*3+2];
        float ddx = dirs[ray*3+0],   ddy = dirs[ray*3+1],   ddz = dirs[ray*3+2];
        float cx = 2.f * (ox + t * ddx);
        float cy = 2.f * (oy + t * ddy);
        float cz = 2.f * (oz + t * ddz);
        int bi = ray >> 12;                   // /NR
        float acc = 0.f;
        #pragma unroll
        for (int p = 0; p < 3; ++p) {
            // plane0:(cx,cy)  plane1:(cx,cz)  plane2:(cz,cx)
            float gx = (p == 2) ? cz : cx;
            float gy = (p == 0) ? cy : ((p == 1) ? cz : cx);
            float fx = (gx + 1.f) * 128.f - 0.5f;
            float fy = (gy + 1.f) * 128.f - 0.5f;
            float x0f = floorf(fx), y0f = floorf(fy);
            float wx = fx - x0f, wy = fy - y0f;
            int x0 = (int)x0f, y0 = (int)y0f;
            // whole-tap early-out: if every corner is out of bounds the
            // reference contribution is exactly 0 -> skip 4 loads + FMAs
            if (x0 >= -1 && x0 <= NW - 1 && y0 >= -1 && y0 <= NH - 1) {
                const float* base = planes_t + (size_t)(bi * 3 + p) * NH * NW * NC;
                float v00 = tapv(base, x0,     y0,     lane);
                float v10 = tapv(base, x0 + 1, y0,     lane);
                float v01 = tapv(base, x0,     y0 + 1, lane);
                float v11 = tapv(base, x0 + 1, y0 + 1, lane);
                acc += v00*(1.f-wx)*(1.f-wy) + v10*wx*(1.f-wy)
                     + v01*(1.f-wx)*wy       + v11*wx*wy;
            }
        }
        xbuf[ls][lane] = acc / 3.f;   // mean over 3 planes
    }
    __syncthreads();

    // MLP: thread-per-sample
    float x[32];
    #pragma unroll
    for (int c = 0; c < 32; ++c) x[c] = xbuf[threadIdx.x][c];
    float o[33];
    #pragma unroll
    for (int k2 = 0; k2 < 33; ++k2) o[k2] = b2s[k2];
    #pragma unroll 1
    for (int j = 0; j < 64; ++j) {
        float a = b1s[j];
        #pragma unroll
        for (int c = 0; c < 32; ++c) a += x[c] * w1s[c * 64 + j];
        float h = softplus_f(a);
        #pragma unroll
        for (int k2 = 0; k2 < 33; ++k2) o[k2] += h * w2s[j * 33 + k2];
    }
    int sg = blockIdx.x * 256 + threadIdx.x;
    sig_out[sg] = o[0];
    #pragma unroll
    for (int c = 0; c < 32; ++c)
        xbuf[threadIdx.x][c] = sigmoid_f(o[1 + c]) * 1.002f - 0.001f;
    __syncthreads();
    // coalesced rgb write (half-wave, lane=channel)
    #pragma unroll 1
    for (int it = 0; it < 32; ++it) {
        int ls = it * 8 + hw;
        rgb_out[(size_t)(blockIdx.x * 256 + ls) * 32 + lane] = xbuf[ls][lane];
    }
}

// ---------------------------------------------------------------------------
// K2: coarse ray-march -> weights -> blur -> PDF -> 48 importance depths.
// Thread-per-ray, fully unrolled register arrays.
// ---------------------------------------------------------------------------
__global__ __launch_bounds__(256) void k_importance(const float* __restrict__ sig,
                                                    float* __restrict__ dfine) {
    int ray = blockIdx.x * 256 + threadIdx.x;
    const float* sp = sig + (size_t)ray * NS;
    float w[47];
    float T = 1.f;
    float sprev = sp[0];
    #pragma unroll
    for (int i = 0; i < 47; ++i) {
        float scur = sp[i + 1];
        float dens = softplus_f(0.5f * (sprev + scur) - 1.f);
        float delta = coarse_depth(i + 1) - coarse_depth(i);
        float alpha = 1.f - __expf(-dens * delta);
        w[i] = alpha * T + 0.01f;            // weights + 0.01
        T *= (1.f - alpha + 1e-10f);
        sprev = scur;
    }
    // blur: wp=[-inf,w,-inf]; nw_i=max(wp_i,wp_{i+1}); wb=0.5*(nw_i+nw_{i+1})+0.01
    // pdf over wb[1..45] (+1e-5 eps)
    float p[45];
    float sum = 0.f;
    #pragma unroll
    for (int i = 1; i <= 45; ++i) {
        float nwi  = fmaxf(w[i - 1], w[i]);
        float nwi1 = fmaxf(w[i], w[i + 1]);
        float wb = 0.5f * (nwi + nwi1) + 0.01f;
        float v = wb + 1e-5f;
        p[i - 1] = v;
        sum += v;
    }
    // walk cdf against monotone u=(k+0.5)/48, searchsorted-right semantics
    int k = 0;
    float cdf_lo = 0.f;
    #pragma unroll
    for (int i = 0; i < 45; ++i) {
        float cdf_hi = cdf_lo + p[i] / sum;
        float bb = zmid_c(i), ba = zmid_c(i + 1);
        float denom = cdf_hi - cdf_lo;
        if (denom < 1e-5f) denom = 1.f;
        while (k < 48) {
            float u = (k + 0.5f) / 48.f;
            if (u < cdf_hi) {
                dfine[(size_t)ray * NS + k] = bb + (u - cdf_lo) / denom * (ba - bb);
                ++k;
            } else break;
        }
        cdf_lo = cdf_hi;
    }
    while (k < 48) {  // u >= cdf[last]: inds clamps, below==above -> bins[45]
        dfine[(size_t)ray * NS + k] = zmid_c(45);
        ++k;
    }
}

// ---------------------------------------------------------------------------
// K4: merge coarse+fine (stable-sort-equivalent ranks), background MLP,
// final ray-march. One wave per ray.
// Phase A (lane=sample-pair): alpha in parallel, T via shfl prefix-product.
// Phase B (lane=channel): pure-FMA color accumulation with coalesced loads.
// ---------------------------------------------------------------------------
__global__ __launch_bounds__(256) void k_final(
    const float* __restrict__ sig_c, const float* __restrict__ rgb_c,
    const float* __restrict__ sig_f, const float* __restrict__ rgb_f,
    const float* __restrict__ dfine,
    const float* __restrict__ dirs, const float* __restrict__ z_bg,
    const float* __restrict__ bw1, const float* __restrict__ bb1,
    const float* __restrict__ bw2, const float* __restrict__ bb2,
    float* __restrict__ out_rgb, float* __restrict__ out_dep,
    float* __restrict__ out_wt)
{
    __shared__ float s_d[4][96];
    __shared__ float s_sig[4][96];
    __shared__ int   s_src[4][96];
    __shared__ float s_fine[4][48];
    __shared__ float s_w[4][96];
    __shared__ float s_g[4][96];
    __shared__ float s_h[4][64];
    __shared__ float s_zb[64];
    int lane = threadIdx.x & 63;
    int wv = threadIdx.x >> 6;
    int ray = blockIdx.x * 4 + wv;
    int bi = (blockIdx.x * 4) >> 12;      // same b for all 4 rays in block
    if (threadIdx.x < 64) s_zb[threadIdx.x] = z_bg[bi * 64 + threadIdx.x];
    if (lane < 48) s_fine[wv][lane] = dfine[(size_t)ray * NS + lane];
    __syncthreads();

    if (lane < 48) {
        // coarse element rank = lane + #{fine < coarse}
        float cd = coarse_depth(lane);
        int lo = 0, hi = 48;
        while (lo < hi) { int mid = (lo + hi) >> 1;
            if (s_fine[wv][mid] < cd) lo = mid + 1; else hi = mid; }
        int rc = lane + lo;
        s_d[wv][rc] = cd;
        s_sig[wv][rc] = sig_c[(size_t)ray * NS + lane];
        s_src[wv][rc] = lane;
        // fine element rank = lane + #{coarse <= fine}
        float f = s_fine[wv][lane];
        lo = 0; hi = 48;
        while (lo < hi) { int mid = (lo + hi) >> 1;
            if (coarse_depth(mid) <= f) lo = mid + 1; else hi = mid; }
        int rf = lane + lo;
        s_d[wv][rf] = f;
        s_sig[wv][rf] = sig_f[(size_t)ray * NS + lane];
        s_src[wv][rf] = 48 + lane;
    }
    float ddx = dirs[ray*3+0], ddy = dirs[ray*3+1], ddz = dirs[ray*3+2];
    __syncthreads();

    // ---- Phase A: per-interval alpha (2 per lane), scan T, weights ----
    float alpha0 = 0.f, alpha1 = 0.f, a0 = 1.f, a1 = 1.f;
    float dm0 = 0.f, dm1 = 0.f;
    if (lane < 48) {
        int i0 = 2 * lane, i1 = i0 + 1;
        float d0 = s_d[wv][i0], sA = s_sig[wv][i0];
        float d1 = s_d[wv][i1], sB = s_sig[wv][i1];
        {
            float dens = softplus_f(0.5f * (sA + sB) - 1.f);
            alpha0 = 1.f - __expf(-dens * (d1 - d0));
            a0 = 1.f - alpha0 + 1e-10f;
            dm0 = 0.5f * (d0 + d1);
        }
        if (i1 < 95) {
            float d2 = s_d[wv][i1 + 1], sC = s_sig[wv][i1 + 1];
            float dens = softplus_f(0.5f * (sB + sC) - 1.f);
            alpha1 = 1.f - __expf(-dens * (d2 - d1));
            a1 = 1.f - alpha1 + 1e-10f;
            dm1 = 0.5f * (d1 + d2);
        }
    }
    // inclusive prefix product of p = a0*a1 across 64 lanes
    float P = a0 * a1;
    #pragma unroll
    for (int off = 1; off < 64; off <<= 1) {
        float t = __shfl_up(P, off);
        if (lane >= off) P *= t;
    }
    float T_all = __shfl(P, 63);          // transmittance after all samples
    float E = __shfl_up(P, 1);            // exclusive
    if (lane == 0) E = 1.f;
    float w0 = alpha0 * E;
    float w1 = alpha1 * (E * a0);
    // depth / weight-total reductions
    float sw = w0 + w1;
    float sd = w0 * dm0 + w1 * dm1;
    #pragma unroll
    for (int off = 32; off; off >>= 1) {
        sw += __shfl_xor(sw, off);
        sd += __shfl_xor(sd, off);
    }
    if (lane < 48) {
        s_w[wv][2 * lane] = w0;
        s_w[wv][2 * lane + 1] = w1;       // lane47 writes w[95]=0
    }
    __syncthreads();
    // per-sample color coefficient g_i = 0.5*(w_{i-1} + w_i), w_{-1}=w_95=0
    {
        int i = lane;
        float wm = (i > 0) ? s_w[wv][i - 1] : 0.f;
        s_g[wv][i] = 0.5f * (wm + s_w[wv][i]);
        int i2 = lane + 64;
        if (lane < 32)
            s_g[wv][i2] = 0.5f * (s_w[wv][i2 - 1] + s_w[wv][i2]);
    }

    // ---- background MLP (lane j computes h_j, then lanes compute o_c) ----
    float a = bb1[lane] + ddx * bw1[lane] + ddy * bw1[64 + lane] + ddz * bw1[128 + lane];
    #pragma unroll 1
    for (int i = 0; i < 64; ++i) a += s_zb[i] * bw1[(3 + i) * 64 + lane];
    s_h[wv][lane] = softplus_f(a);
    __syncthreads();
    int c = lane & 31;
    float ob = bb2[c];
    #pragma unroll 1
    for (int j = 0; j < 64; ++j) ob += s_h[wv][j] * bw2[j * 32 + c];
    float bgc = sigmoid_f(ob);

    // ---- Phase B: color accumulation, lane = (channel, half) ----
    int h = lane >> 5;
    size_t rbase = (size_t)ray * NS * 32;
    const float* b0p = rgb_c + rbase;
    const float* b1p = rgb_f + rbase - (size_t)48 * 32;
    float acc = 0.f;
    #pragma unroll 4
    for (int i = h; i < 96; i += 2) {
        int src = s_src[wv][i];
        const float* cp = ((src < 48) ? b0p : b1p) + (size_t)src * 32;
        acc += s_g[wv][i] * cp[c];
    }
    acc += __shfl_xor(acc, 32);

    float rgbv = (acc + T_all * bgc) * 2.f - 1.f;
    float dep = sd / sw;
    if (!(dep == dep)) dep = INFINITY;          // nan_to_num(nan -> inf)
    dep = fminf(fmaxf(dep, coarse_depth(0)), coarse_depth(47));
    if (lane < 32) out_rgb[(size_t)ray * 32 + c] = rgbv;
    if (lane == 0) { out_dep[ray] = dep; out_wt[ray] = sw; }
}

// ---------------------------------------------------------------------------
extern "C" void kernel_launch(void* const* d_in, const int* in_sizes, int n_in,
                              void* d_out, int out_size, void* d_ws, size_t ws_size,
                              hipStream_t stream) {
    (void)in_sizes; (void)n_in; (void)out_size; (void)ws_size;
    const float* planes  = (const float*)d_in[0];
    const float* origins = (const float*)d_in[1];
    const float* dirs    = (const float*)d_in[2];
    const float* z_bg    = (const float*)d_in[3];
    const float* dw1     = (const float*)d_in[4];
    const float* db1     = (const float*)d_in[5];
    const float* dw2     = (const float*)d_in[6];
    const float* db2     = (const float*)d_in[7];
    const float* bw1     = (const float*)d_in[8];
    const float* bb1     = (const float*)d_in[9];
    const float* bw2     = (const float*)d_in[10];
    const float* bb2     = (const float*)d_in[11];

    // workspace layout (f32): total ~297 MiB
    char* ws = (char*)d_ws;
    size_t off = 0;
    float* planes_t = (float*)(ws + off); off += (size_t)NB * 3 * NH * NW * NC * 4;
    float* rgb_c    = (float*)(ws + off); off += (size_t)NSAMP * 32 * 4;
    float* rgb_f    = (float*)(ws + off); off += (size_t)NSAMP * 32 * 4;
    float* sig_c    = (float*)(ws + off); off += (size_t)NSAMP * 4;
    float* sig_f    = (float*)(ws + off); off += (size_t)NSAMP * 4;
    float* dfine    = (float*)(ws + off); off += (size_t)NSAMP * 4;

    float* out_rgb = (float*)d_out;
    float* out_dep = out_rgb + (size_t)NRAYS * 32;
    float* out_wt  = out_dep + NRAYS;

    k_transpose<<<dim3(NB * 3 * 1024), dim3(256), 0, stream>>>(planes, planes_t);
    k_sample_decode<false><<<dim3(NSAMP / 256), dim3(256), 0, stream>>>(
        planes_t, origins, dirs, (const float*)nullptr,
        dw1, db1, dw2, db2, rgb_c, sig_c);
    k_importance<<<dim3(NRAYS / 256), dim3(256), 0, stream>>>(sig_c, dfine);
    k_sample_decode<true><<<dim3(NSAMP / 256), dim3(256), 0, stream>>>(
        planes_t, origins, dirs, dfine,
        dw1, db1, dw2, db2, rgb_f, sig_f);
    k_final<<<dim3(NRAYS / 4), dim3(256), 0, stream>>>(
        sig_c, rgb_c, sig_f, rgb_f, dfine, dirs, z_bg,
        bw1, bb1, bw2, bb2, out_rgb, out_dep, out_wt);
}

// Round 4
// 893.715 us; speedup vs baseline: 1.5165x; 1.0135x over previous
//
#include <hip/hip_runtime.h>
#include <hip/hip_bf16.h>
#include <math.h>

// Problem constants (fixed by reference)
#define NB 4
#define NR 4096
#define NC 32
#define NH 256
#define NW 256
#define NS 48
#define NRAYS (NB*NR)          // 16384
#define NSAMP (NRAYS*NS)       // 786432

__device__ __forceinline__ float coarse_depth(int i) {
    const float DELTA = 1.05f / 47.f;
    return 2.25f + i * DELTA + 0.5f * DELTA;
}
__device__ __forceinline__ float zmid_c(int i) {
    return 0.5f * (coarse_depth(i) + coarse_depth(i + 1));
}
// fast softplus: max(x,0) + log(1+exp(-|x|)) via v_exp_f32/v_log_f32
__device__ __forceinline__ float softplus_f(float x) {
    return fmaxf(x, 0.f) + __logf(1.f + __expf(-fabsf(x)));
}
__device__ __forceinline__ float sigmoid_f(float x) {
    return __frcp_rn(1.f + __expf(-x));
}

// ---------------------------------------------------------------------------
// K0: transpose planes (B,3,C,H,W) -> channel-interleaved (B*3, H*W, C)
// so one sample tap = 32 contiguous floats (128B line).
// ---------------------------------------------------------------------------
__global__ __launch_bounds__(256) void k_transpose(const float* __restrict__ in,
                                                   float* __restrict__ out) {
    __shared__ float tile[32][65];
    int bp = blockIdx.x >> 10;            // 0..11  (b*3+p)
    int t0 = (blockIdx.x & 1023) * 64;    // pixel base within 65536
    const float* src = in + (size_t)bp * NC * NH * NW;
    float* dst = out + (size_t)bp * NH * NW * NC;
    int px = threadIdx.x & 63;
    int c0 = threadIdx.x >> 6;            // 0..3
    #pragma unroll
    for (int cc = 0; cc < 32; cc += 4)
        tile[cc + c0][px] = src[(size_t)(cc + c0) * NH * NW + t0 + px];
    __syncthreads();
    int c = threadIdx.x & 31;
    int p0 = threadIdx.x >> 5;            // 0..7
    #pragma unroll
    for (int pp = 0; pp < 64; pp += 8)
        dst[(size_t)(t0 + pp + p0) * NC + c] = tile[c][pp + p0];
}

// ---------------------------------------------------------------------------
// K_const: MLP output for all-zero features (fully-out-of-bounds samples).
// const_o[0] = sigma, const_o[1..32] = activated rgb.
// ---------------------------------------------------------------------------
__global__ __launch_bounds__(64) void k_const(const float* __restrict__ b1,
                                              const float* __restrict__ w2,
                                              const float* __restrict__ b2,
                                              float* __restrict__ const_o) {
    __shared__ float h[64];
    int j = threadIdx.x;
    h[j] = softplus_f(b1[j]);
    __syncthreads();
    if (j < 33) {
        float o = b2[j];
        #pragma unroll 1
        for (int i = 0; i < 64; ++i) o += h[i] * w2[i * 33 + j];
        const_o[j] = (j == 0) ? o : sigmoid_f(o) * 1.002f - 0.001f;
    }
}

// ---------------------------------------------------------------------------
// K1/K3: sample tri-planes + decode MLP.
// Phase 1 (wave-local, lane=sample): address math + per-corner-zeroed weights
//   computed ONCE per sample into registers (was 32x redundant).
// Phase 2 (half-wave, lane=channel): meta via __shfl broadcast, 4 coalesced
//   taps per plane at fixed offsets (validity pre-folded into weights).
// MLP (thread-per-sample): w1 transposed + w2 padded for ds_read_b128;
//   fully-out samples take the precomputed const path.
// ---------------------------------------------------------------------------
template<bool FINE>
__global__ __launch_bounds__(256) void k_sample_decode(
    const float* __restrict__ planes_t,
    const float* __restrict__ origins,
    const float* __restrict__ dirs,
    const float* __restrict__ dfine,       // null for coarse
    const float* __restrict__ w1, const float* __restrict__ b1,
    const float* __restrict__ w2, const float* __restrict__ b2,
    const float* __restrict__ const_o,
    float* __restrict__ rgb_out, float* __restrict__ sig_out)
{
    __shared__ float xbuf[256][33];   // +1 pad vs 32: kills bank conflicts
    __shared__ float w1t[64][32];     // w1t[j][c] = w1[c*64+j], b128-friendly
    __shared__ float w2p[64][36];     // rows padded 33->36 (16B aligned)
    __shared__ float b1s[64];
    __shared__ float b2s[36];
    __shared__ float cbuf[36];        // const MLP output (empty samples)

    for (int i = threadIdx.x; i < 2048; i += 256) {
        int j = i >> 5, c = i & 31;
        w1t[j][c] = w1[c * 64 + j];
    }
    for (int i = threadIdx.x; i < 64 * 36; i += 256) {
        int j = i / 36, kx = i - j * 36;
        w2p[j][kx] = (kx < 33) ? w2[j * 33 + kx] : 0.f;
    }
    if (threadIdx.x < 64) b1s[threadIdx.x] = b1[threadIdx.x];
    if (threadIdx.x < 36) {
        b2s[threadIdx.x]  = (threadIdx.x < 33) ? b2[threadIdx.x] : 0.f;
        cbuf[threadIdx.x] = (threadIdx.x < 33) ? const_o[threadIdx.x] : 0.f;
    }

    int lane  = threadIdx.x & 63;
    int wbase = threadIdx.x & 192;        // (tid>>6)*64: wave's sample base
    int s0    = blockIdx.x * 256 + wbase;

    // ---- phase 1: meta for OWN sample (registers) ----
    int s   = s0 + lane;
    int ray = s / NS;
    int kk  = s - ray * NS;
    float t = FINE ? dfine[s] : coarse_depth(kk);
    float ox = origins[ray*3+0], oy = origins[ray*3+1], oz = origins[ray*3+2];
    float ddx = dirs[ray*3+0],   ddy = dirs[ray*3+1],   ddz = dirs[ray*3+2];
    float cx = 2.f * (ox + t * ddx);
    float cy = 2.f * (oy + t * ddy);
    float cz = 2.f * (oz + t * ddz);
    int bi = ray >> 12;                   // /NR
    int   m_base[3];
    float m_q[3][4];
    #pragma unroll
    for (int p = 0; p < 3; ++p) {
        // plane0:(cx,cy)  plane1:(cx,cz)  plane2:(cz,cx)
        float gx = (p == 2) ? cz : cx;
        float gy = (p == 0) ? cy : ((p == 1) ? cz : cx);
        float fx = (gx + 1.f) * 128.f - 0.5f;
        float fy = (gy + 1.f) * 128.f - 0.5f;
        float x0f = floorf(fx), y0f = floorf(fy);
        float wx = fx - x0f, wy = fy - y0f;
        int x0 = (int)x0f, y0 = (int)y0f;
        if (x0 >= -1 && x0 <= 255 && y0 >= -1 && y0 <= 255) {
            float wxm = 1.f - wx, wym = 1.f - wy;
            float q00 = wxm*wym, q10 = wx*wym, q01 = wxm*wy, q11 = wx*wy;
            // per-corner validity folded into weights (== reference mask)
            if (!(x0 >= 0   && y0 >= 0))   q00 = 0.f;
            if (!(x0 <= 254 && y0 >= 0))   q10 = 0.f;
            if (!(x0 >= 0   && y0 <= 254)) q01 = 0.f;
            if (!(x0 <= 254 && y0 <= 254)) q11 = 0.f;
            // NOTE: base may be up to 8224 elems before the plane (x0=y0=-1),
            // those reads land in the sigma/dfine buffers that precede
            // planes_t in ws — in-bounds, finite, and multiplied by 0.
            m_base[p] = (bi*3 + p) * (NH*NW*NC) + (y0*NW + x0)*NC;
            m_q[p][0] = q00; m_q[p][1] = q10; m_q[p][2] = q01; m_q[p][3] = q11;
        } else {
            m_base[p] = -1;               // fully out: skip sentinel
            m_q[p][0] = m_q[p][1] = m_q[p][2] = m_q[p][3] = 0.f;
        }
    }

    // ---- phase 2: gather (2 samples/iter, half-wave lane=channel) ----
    int ch   = lane & 31;
    int half = lane >> 5;
    #pragma unroll 1
    for (int i = 0; i < 64; i += 2) {
        int src = i + half;               // meta source lane
        float acc = 0.f;
        #pragma unroll
        for (int p = 0; p < 3; ++p) {
            int   bse = __shfl(m_base[p], src);
            float q00 = __shfl(m_q[p][0], src);
            float q10 = __shfl(m_q[p][1], src);
            float q01 = __shfl(m_q[p][2], src);
            float q11 = __shfl(m_q[p][3], src);
            if (bse >= 0) {
                const float* ptr = planes_t + (size_t)bse + ch;
                acc += q00 * ptr[0]    + q10 * ptr[32]
                     + q01 * ptr[8192] + q11 * ptr[8224];
            }
        }
        xbuf[wbase + i + half][ch] = acc * (1.f / 3.f);
    }
    __syncthreads();

    // ---- MLP: thread-per-sample (own sample == phase-1 sample) ----
    bool empty = (m_base[0] < 0) & (m_base[1] < 0) & (m_base[2] < 0);
    float sig;
    if (!empty) {
        float x[32];
        #pragma unroll
        for (int c = 0; c < 32; ++c) x[c] = xbuf[threadIdx.x][c];
        float o[36];
        #pragma unroll
        for (int k2 = 0; k2 < 36; ++k2) o[k2] = b2s[k2];
        #pragma unroll 1
        for (int j = 0; j < 64; ++j) {
            float a = b1s[j];
            #pragma unroll
            for (int c = 0; c < 32; ++c) a += x[c] * w1t[j][c];
            float h = softplus_f(a);
            #pragma unroll
            for (int k2 = 0; k2 < 36; ++k2) o[k2] += h * w2p[j][k2];
        }
        sig = o[0];
        #pragma unroll
        for (int c = 0; c < 32; ++c)
            xbuf[threadIdx.x][c] = sigmoid_f(o[1 + c]) * 1.002f - 0.001f;
    } else {
        sig = cbuf[0];
        #pragma unroll
        for (int c = 0; c < 32; ++c) xbuf[threadIdx.x][c] = cbuf[1 + c];
    }
    sig_out[s] = sig;
    __syncthreads();

    // ---- coalesced rgb write (half-wave, lane=channel) ----
    #pragma unroll 1
    for (int i = 0; i < 64; i += 2) {
        int r = wbase + i + half;
        rgb_out[(size_t)(blockIdx.x * 256 + r) * 32 + ch] = xbuf[r][ch];
    }
}

// ---------------------------------------------------------------------------
// K2: coarse ray-march -> weights -> blur -> PDF -> 48 importance depths.
// Thread-per-ray, fully unrolled register arrays.
// ---------------------------------------------------------------------------
__global__ __launch_bounds__(256) void k_importance(const float* __restrict__ sig,
                                                    float* __restrict__ dfine) {
    int ray = blockIdx.x * 256 + threadIdx.x;
    const float* sp = sig + (size_t)ray * NS;
    float w[47];
    float T = 1.f;
    float sprev = sp[0];
    #pragma unroll
    for (int i = 0; i < 47; ++i) {
        float scur = sp[i + 1];
        float dens = softplus_f(0.5f * (sprev + scur) - 1.f);
        float delta = coarse_depth(i + 1) - coarse_depth(i);
        float alpha = 1.f - __expf(-dens * delta);
        w[i] = alpha * T + 0.01f;            // weights + 0.01
        T *= (1.f - alpha + 1e-10f);
        sprev = scur;
    }
    // blur: wp=[-inf,w,-inf]; nw_i=max(wp_i,wp_{i+1}); wb=0.5*(nw_i+nw_{i+1})+0.01
    // pdf over wb[1..45] (+1e-5 eps)
    float p[45];
    float sum = 0.f;
    #pragma unroll
    for (int i = 1; i <= 45; ++i) {
        float nwi  = fmaxf(w[i - 1], w[i]);
        float nwi1 = fmaxf(w[i], w[i + 1]);
        float wb = 0.5f * (nwi + nwi1) + 0.01f;
        float v = wb + 1e-5f;
        p[i - 1] = v;
        sum += v;
    }
    // walk cdf against monotone u=(k+0.5)/48, searchsorted-right semantics
    int k = 0;
    float cdf_lo = 0.f;
    #pragma unroll
    for (int i = 0; i < 45; ++i) {
        float cdf_hi = cdf_lo + p[i] / sum;
        float bb = zmid_c(i), ba = zmid_c(i + 1);
        float denom = cdf_hi - cdf_lo;
        if (denom < 1e-5f) denom = 1.f;
        while (k < 48) {
            float u = (k + 0.5f) / 48.f;
            if (u < cdf_hi) {
                dfine[(size_t)ray * NS + k] = bb + (u - cdf_lo) / denom * (ba - bb);
                ++k;
            } else break;
        }
        cdf_lo = cdf_hi;
    }
    while (k < 48) {  // u >= cdf[last]: inds clamps, below==above -> bins[45]
        dfine[(size_t)ray * NS + k] = zmid_c(45);
        ++k;
    }
}

// ---------------------------------------------------------------------------
// K4: merge coarse+fine (stable-sort-equivalent ranks), background MLP,
// final ray-march. One wave per ray.
// Phase A (lane=sample-pair): alpha in parallel, T via shfl prefix-product.
// Phase B (lane=channel): pure-FMA color accumulation with coalesced loads.
// ---------------------------------------------------------------------------
__global__ __launch_bounds__(256) void k_final(
    const float* __restrict__ sig_c, const float* __restrict__ rgb_c,
    const float* __restrict__ sig_f, const float* __restrict__ rgb_f,
    const float* __restrict__ dfine,
    const float* __restrict__ dirs, const float* __restrict__ z_bg,
    const float* __restrict__ bw1, const float* __restrict__ bb1,
    const float* __restrict__ bw2, const float* __restrict__ bb2,
    float* __restrict__ out_rgb, float* __restrict__ out_dep,
    float* __restrict__ out_wt)
{
    __shared__ float s_d[4][96];
    __shared__ float s_sig[4][96];
    __shared__ int   s_src[4][96];
    __shared__ float s_fine[4][48];
    __shared__ float s_w[4][96];
    __shared__ float s_g[4][96];
    __shared__ float s_h[4][64];
    __shared__ float s_zb[64];
    int lane = threadIdx.x & 63;
    int wv = threadIdx.x >> 6;
    int ray = blockIdx.x * 4 + wv;
    int bi = (blockIdx.x * 4) >> 12;      // same b for all 4 rays in block
    if (threadIdx.x < 64) s_zb[threadIdx.x] = z_bg[bi * 64 + threadIdx.x];
    if (lane < 48) s_fine[wv][lane] = dfine[(size_t)ray * NS + lane];
    __syncthreads();

    if (lane < 48) {
        // coarse element rank = lane + #{fine < coarse}
        float cd = coarse_depth(lane);
        int lo = 0, hi = 48;
        while (lo < hi) { int mid = (lo + hi) >> 1;
            if (s_fine[wv][mid] < cd) lo = mid + 1; else hi = mid; }
        int rc = lane + lo;
        s_d[wv][rc] = cd;
        s_sig[wv][rc] = sig_c[(size_t)ray * NS + lane];
        s_src[wv][rc] = lane;
        // fine element rank = lane + #{coarse <= fine}
        float f = s_fine[wv][lane];
        lo = 0; hi = 48;
        while (lo < hi) { int mid = (lo + hi) >> 1;
            if (coarse_depth(mid) <= f) lo = mid + 1; else hi = mid; }
        int rf = lane + lo;
        s_d[wv][rf] = f;
        s_sig[wv][rf] = sig_f[(size_t)ray * NS + lane];
        s_src[wv][rf] = 48 + lane;
    }
    float ddx = dirs[ray*3+0], ddy = dirs[ray*3+1], ddz = dirs[ray*3+2];
    __syncthreads();

    // ---- Phase A: per-interval alpha (2 per lane), scan T, weights ----
    float alpha0 = 0.f, alpha1 = 0.f, a0 = 1.f, a1 = 1.f;
    float dm0 = 0.f, dm1 = 0.f;
    if (lane < 48) {
        int i0 = 2 * lane, i1 = i0 + 1;
        float d0 = s_d[wv][i0], sA = s_sig[wv][i0];
        float d1 = s_d[wv][i1], sB = s_sig[wv][i1];
        {
            float dens = softplus_f(0.5f * (sA + sB) - 1.f);
            alpha0 = 1.f - __expf(-dens * (d1 - d0));
            a0 = 1.f - alpha0 + 1e-10f;
            dm0 = 0.5f * (d0 + d1);
        }
        if (i1 < 95) {
            float d2 = s_d[wv][i1 + 1], sC = s_sig[wv][i1 + 1];
            float dens = softplus_f(0.5f * (sB + sC) - 1.f);
            alpha1 = 1.f - __expf(-dens * (d2 - d1));
            a1 = 1.f - alpha1 + 1e-10f;
            dm1 = 0.5f * (d1 + d2);
        }
    }
    // inclusive prefix product of p = a0*a1 across 64 lanes
    float P = a0 * a1;
    #pragma unroll
    for (int off = 1; off < 64; off <<= 1) {
        float t = __shfl_up(P, off);
        if (lane >= off) P *= t;
    }
    float T_all = __shfl(P, 63);          // transmittance after all samples
    float E = __shfl_up(P, 1);            // exclusive
    if (lane == 0) E = 1.f;
    float w0 = alpha0 * E;
    float w1 = alpha1 * (E * a0);
    // depth / weight-total reductions
    float sw = w0 + w1;
    float sd = w0 * dm0 + w1 * dm1;
    #pragma unroll
    for (int off = 32; off; off >>= 1) {
        sw += __shfl_xor(sw, off);
        sd += __shfl_xor(sd, off);
    }
    if (lane < 48) {
        s_w[wv][2 * lane] = w0;
        s_w[wv][2 * lane + 1] = w1;       // lane47 writes w[95]=0
    }
    __syncthreads();
    // per-sample color coefficient g_i = 0.5*(w_{i-1} + w_i), w_{-1}=w_95=0
    {
        int i = lane;
        float wm = (i > 0) ? s_w[wv][i - 1] : 0.f;
        s_g[wv][i] = 0.5f * (wm + s_w[wv][i]);
        int i2 = lane + 64;
        if (lane < 32)
            s_g[wv][i2] = 0.5f * (s_w[wv][i2 - 1] + s_w[wv][i2]);
    }

    // ---- background MLP (lane j computes h_j, then lanes compute o_c) ----
    float a = bb1[lane] + ddx * bw1[lane] + ddy * bw1[64 + lane] + ddz * bw1[128 + lane];
    #pragma unroll 1
    for (int i = 0; i < 64; ++i) a += s_zb[i] * bw1[(3 + i) * 64 + lane];
    s_h[wv][lane] = softplus_f(a);
    __syncthreads();
    int c = lane & 31;
    float ob = bb2[c];
    #pragma unroll 1
    for (int j = 0; j < 64; ++j) ob += s_h[wv][j] * bw2[j * 32 + c];
    float bgc = sigmoid_f(ob);

    // ---- Phase B: color accumulation, lane = (channel, half) ----
    int h = lane >> 5;
    size_t rbase = (size_t)ray * NS * 32;
    const float* b0p = rgb_c + rbase;
    const float* b1p = rgb_f + rbase - (size_t)48 * 32;
    float acc = 0.f;
    #pragma unroll 4
    for (int i = h; i < 96; i += 2) {
        int src = s_src[wv][i];
        const float* cp = ((src < 48) ? b0p : b1p) + (size_t)src * 32;
        acc += s_g[wv][i] * cp[c];
    }
    acc += __shfl_xor(acc, 32);

    float rgbv = (acc + T_all * bgc) * 2.f - 1.f;
    float dep = sd / sw;
    if (!(dep == dep)) dep = INFINITY;          // nan_to_num(nan -> inf)
    dep = fminf(fmaxf(dep, coarse_depth(0)), coarse_depth(47));
    if (lane < 32) out_rgb[(size_t)ray * 32 + c] = rgbv;
    if (lane == 0) { out_dep[ray] = dep; out_wt[ray] = sw; }
}

// ---------------------------------------------------------------------------
extern "C" void kernel_launch(void* const* d_in, const int* in_sizes, int n_in,
                              void* d_out, int out_size, void* d_ws, size_t ws_size,
                              hipStream_t stream) {
    (void)in_sizes; (void)n_in; (void)out_size; (void)ws_size;
    const float* planes  = (const float*)d_in[0];
    const float* origins = (const float*)d_in[1];
    const float* dirs    = (const float*)d_in[2];
    const float* z_bg    = (const float*)d_in[3];
    const float* dw1     = (const float*)d_in[4];
    const float* db1     = (const float*)d_in[5];
    const float* dw2     = (const float*)d_in[6];
    const float* db2     = (const float*)d_in[7];
    const float* bw1     = (const float*)d_in[8];
    const float* bb1     = (const float*)d_in[9];
    const float* bw2     = (const float*)d_in[10];
    const float* bb2     = (const float*)d_in[11];

    // workspace layout (f32), ~311 MiB total.
    // Small buffers FIRST so planes_t has a 9MB guard region before it
    // (boundary taps with zeroed weights may read up to ~33KB before a plane).
    char* ws = (char*)d_ws;
    size_t off = 0;
    float* sig_c    = (float*)(ws + off); off += (size_t)NSAMP * 4;
    float* sig_f    = (float*)(ws + off); off += (size_t)NSAMP * 4;
    float* dfine    = (float*)(ws + off); off += (size_t)NSAMP * 4;
    float* const_o  = (float*)(ws + off); off += 4096;
    float* planes_t = (float*)(ws + off); off += (size_t)NB * 3 * NH * NW * NC * 4;
    float* rgb_c    = (float*)(ws + off); off += (size_t)NSAMP * 32 * 4;
    float* rgb_f    = (float*)(ws + off); off += (size_t)NSAMP * 32 * 4;

    float* out_rgb = (float*)d_out;
    float* out_dep = out_rgb + (size_t)NRAYS * 32;
    float* out_wt  = out_dep + NRAYS;

    k_const<<<dim3(1), dim3(64), 0, stream>>>(db1, dw2, db2, const_o);
    k_transpose<<<dim3(NB * 3 * 1024), dim3(256), 0, stream>>>(planes, planes_t);
    k_sample_decode<false><<<dim3(NSAMP / 256), dim3(256), 0, stream>>>(
        planes_t, origins, dirs, (const float*)nullptr,
        dw1, db1, dw2, db2, const_o, rgb_c, sig_c);
    k_importance<<<dim3(NRAYS / 256), dim3(256), 0, stream>>>(sig_c, dfine);
    k_sample_decode<true><<<dim3(NSAMP / 256), dim3(256), 0, stream>>>(
        planes_t, origins, dirs, dfine,
        dw1, db1, dw2, db2, const_o, rgb_f, sig_f);
    k_final<<<dim3(NRAYS / 4), dim3(256), 0, stream>>>(
        sig_c, rgb_c, sig_f, rgb_f, dfine, dirs, z_bg,
        bw1, bb1, bw2, bb2, out_rgb, out_dep, out_wt);
}

// Round 6
// 772.083 us; speedup vs baseline: 1.7554x; 1.1575x over previous
//
#include <hip/hip_runtime.h>
#include <hip/hip_bf16.h>
#include <math.h>

// Problem constants (fixed by reference)
#define NB 4
#define NR 4096
#define NC 32
#define NH 256
#define NW 256
#define NS 48
#define NRAYS (NB*NR)          // 16384
#define NSAMP (NRAYS*NS)       // 786432

__device__ __forceinline__ float coarse_depth(int i) {
    const float DELTA = 1.05f / 47.f;
    return 2.25f + i * DELTA + 0.5f * DELTA;
}
__device__ __forceinline__ float zmid_c(int i) {
    return 0.5f * (coarse_depth(i) + coarse_depth(i + 1));
}
// fast softplus: max(x,0) + log(1+exp(-|x|)) via v_exp_f32/v_log_f32
__device__ __forceinline__ float softplus_f(float x) {
    return fmaxf(x, 0.f) + __logf(1.f + __expf(-fabsf(x)));
}
__device__ __forceinline__ float sigmoid_f(float x) {
    return __frcp_rn(1.f + __expf(-x));
}

// ---------------------------------------------------------------------------
// K0: transpose planes (B,3,C,H,W) -> channel-interleaved (B*3, H*W, C)
// so one sample tap = 32 contiguous floats (128B line).
// ---------------------------------------------------------------------------
__global__ __launch_bounds__(256) void k_transpose(const float* __restrict__ in,
                                                   float* __restrict__ out) {
    __shared__ float tile[32][65];
    int bp = blockIdx.x >> 10;            // 0..11  (b*3+p)
    int t0 = (blockIdx.x & 1023) * 64;    // pixel base within 65536
    const float* src = in + (size_t)bp * NC * NH * NW;
    float* dst = out + (size_t)bp * NH * NW * NC;
    int px = threadIdx.x & 63;
    int c0 = threadIdx.x >> 6;            // 0..3
    #pragma unroll
    for (int cc = 0; cc < 32; cc += 4)
        tile[cc + c0][px] = src[(size_t)(cc + c0) * NH * NW + t0 + px];
    __syncthreads();
    int c = threadIdx.x & 31;
    int p0 = threadIdx.x >> 5;            // 0..7
    #pragma unroll
    for (int pp = 0; pp < 64; pp += 8)
        dst[(size_t)(t0 + pp + p0) * NC + c] = tile[c][pp + p0];
}

// ---------------------------------------------------------------------------
// K_prep: w1 transposed to [64][32] and w2 row-padded to [64][36] in ws,
// so the MLP kernel's uniform weight reads are contiguous (s_load-friendly).
// ---------------------------------------------------------------------------
__global__ __launch_bounds__(256) void k_prep(const float* __restrict__ w1,
                                              const float* __restrict__ w2,
                                              float* __restrict__ w1t,
                                              float* __restrict__ w2p) {
    for (int i = threadIdx.x; i < 2048; i += 256) {
        int j = i >> 5, c = i & 31;
        w1t[j * 32 + c] = w1[c * 64 + j];
    }
    for (int i = threadIdx.x; i < 64 * 36; i += 256) {
        int j = i / 36, kx = i - j * 36;
        w2p[i] = (kx < 33) ? w2[j * 33 + kx] : 0.f;
    }
}

// ---------------------------------------------------------------------------
// K1a/K3a: tri-plane gather. NO LDS -> occupancy is VGPR-bound (~7-8 w/SIMD)
// so the scattered L2/L3 tap latency is hidden by TLP.
// Phase 1 (lane=sample): address math + per-corner-zeroed weights, once.
// Phase 2 (half-wave, lane=channel): meta via __shfl, coalesced taps,
// features written straight to global (aliases the rgb buffer).
// ---------------------------------------------------------------------------
template<bool FINE>
__global__ __launch_bounds__(256) void k_gather(
    const float* __restrict__ planes_t,
    const float* __restrict__ origins,
    const float* __restrict__ dirs,
    const float* __restrict__ dfine,       // null for coarse
    float* __restrict__ feats_out)         // [NSAMP][32]
{
    int lane  = threadIdx.x & 63;
    int wbase = threadIdx.x & 192;        // (tid>>6)*64: wave's sample base
    int s0    = blockIdx.x * 256 + wbase;

    // ---- phase 1: meta for OWN sample (registers) ----
    int s   = s0 + lane;
    int ray = s / NS;
    int kk  = s - ray * NS;
    float t = FINE ? dfine[s] : coarse_depth(kk);
    float ox = origins[ray*3+0], oy = origins[ray*3+1], oz = origins[ray*3+2];
    float ddx = dirs[ray*3+0],   ddy = dirs[ray*3+1],   ddz = dirs[ray*3+2];
    float cx = 2.f * (ox + t * ddx);
    float cy = 2.f * (oy + t * ddy);
    float cz = 2.f * (oz + t * ddz);
    int bi = ray >> 12;                   // /NR
    int   m_base[3];
    float m_q[3][4];
    #pragma unroll
    for (int p = 0; p < 3; ++p) {
        // plane0:(cx,cy)  plane1:(cx,cz)  plane2:(cz,cx)
        float gx = (p == 2) ? cz : cx;
        float gy = (p == 0) ? cy : ((p == 1) ? cz : cx);
        float fx = (gx + 1.f) * 128.f - 0.5f;
        float fy = (gy + 1.f) * 128.f - 0.5f;
        float x0f = floorf(fx), y0f = floorf(fy);
        float wx = fx - x0f, wy = fy - y0f;
        int x0 = (int)x0f, y0 = (int)y0f;
        if (x0 >= -1 && x0 <= 255 && y0 >= -1 && y0 <= 255) {
            float wxm = 1.f - wx, wym = 1.f - wy;
            float q00 = wxm*wym, q10 = wx*wym, q01 = wxm*wy, q11 = wx*wy;
            // per-corner validity folded into weights (== reference mask)
            if (!(x0 >= 0   && y0 >= 0))   q00 = 0.f;
            if (!(x0 <= 254 && y0 >= 0))   q10 = 0.f;
            if (!(x0 >= 0   && y0 <= 254)) q01 = 0.f;
            if (!(x0 <= 254 && y0 <= 254)) q11 = 0.f;
            // NOTE: base may be up to 8224 elems before the plane (x0=y0=-1),
            // those reads land in the sigma/dfine buffers that precede
            // planes_t in ws — in-bounds, finite, and multiplied by 0.
            m_base[p] = (bi*3 + p) * (NH*NW*NC) + (y0*NW + x0)*NC;
            m_q[p][0] = q00; m_q[p][1] = q10; m_q[p][2] = q01; m_q[p][3] = q11;
        } else {
            m_base[p] = -1;               // fully out: skip sentinel
            m_q[p][0] = m_q[p][1] = m_q[p][2] = m_q[p][3] = 0.f;
        }
    }

    // ---- phase 2: gather (2 samples/iter, half-wave lane=channel) ----
    int ch   = lane & 31;
    int half = lane >> 5;
    #pragma unroll 1
    for (int i = 0; i < 64; i += 2) {
        int src = i + half;               // meta source lane
        float acc = 0.f;
        #pragma unroll
        for (int p = 0; p < 3; ++p) {
            int   bse = __shfl(m_base[p], src);
            float q00 = __shfl(m_q[p][0], src);
            float q10 = __shfl(m_q[p][1], src);
            float q01 = __shfl(m_q[p][2], src);
            float q11 = __shfl(m_q[p][3], src);
            if (bse >= 0) {
                const float* ptr = planes_t + (size_t)bse + ch;
                acc += q00 * ptr[0]    + q10 * ptr[32]
                     + q01 * ptr[8192] + q11 * ptr[8224];
            }
        }
        feats_out[(size_t)(s0 + i + half) * 32 + ch] = acc * (1.f / 3.f);
    }
}

// ---------------------------------------------------------------------------
// K1b/K3b: decode MLP, thread-per-sample, IN-PLACE (feats -> rgb).
// x[32] read as 8x float4 (wave window = contiguous 8KB -> L1-resident).
// Weights read via uniform const-restrict global access -> scalar-promoted
// to s_load (SGPR operands), no LDS at all.
// ---------------------------------------------------------------------------
__global__ __launch_bounds__(256) void k_mlp(
    const float* __restrict__ w1t,   // [64][32]
    const float* __restrict__ b1,
    const float* __restrict__ w2p,   // [64][36] (rows padded)
    const float* __restrict__ b2,
    float* __restrict__ rgb_io,      // in: feats, out: rgb
    float* __restrict__ sig_out)
{
    int s = blockIdx.x * 256 + threadIdx.x;
    float* base = rgb_io + (size_t)s * 32;
    float x[32];
    #pragma unroll
    for (int i = 0; i < 8; ++i) {
        float4 v = ((const float4*)base)[i];
        x[4*i+0] = v.x; x[4*i+1] = v.y; x[4*i+2] = v.z; x[4*i+3] = v.w;
    }
    float o[33];
    #pragma unroll
    for (int k2 = 0; k2 < 33; ++k2) o[k2] = b2[k2];
    #pragma unroll 4
    for (int j = 0; j < 64; ++j) {
        float a = b1[j];
        #pragma unroll
        for (int c = 0; c < 32; ++c) a += x[c] * w1t[j * 32 + c];
        float h = softplus_f(a);
        #pragma unroll
        for (int k2 = 0; k2 < 33; ++k2) o[k2] += h * w2p[j * 36 + k2];
    }
    sig_out[s] = o[0];
    #pragma unroll
    for (int i = 0; i < 8; ++i) {
        float4 r;
        r.x = sigmoid_f(o[1 + 4*i + 0]) * 1.002f - 0.001f;
        r.y = sigmoid_f(o[1 + 4*i + 1]) * 1.002f - 0.001f;
        r.z = sigmoid_f(o[1 + 4*i + 2]) * 1.002f - 0.001f;
        r.w = sigmoid_f(o[1 + 4*i + 3]) * 1.002f - 0.001f;
        ((float4*)base)[i] = r;
    }
}

// ---------------------------------------------------------------------------
// K2: coarse ray-march -> weights -> blur -> PDF -> 48 importance depths.
// Thread-per-ray, fully unrolled register arrays.
// ---------------------------------------------------------------------------
__global__ __launch_bounds__(256) void k_importance(const float* __restrict__ sig,
                                                    float* __restrict__ dfine) {
    int ray = blockIdx.x * 256 + threadIdx.x;
    const float* sp = sig + (size_t)ray * NS;
    float w[47];
    float T = 1.f;
    float sprev = sp[0];
    #pragma unroll
    for (int i = 0; i < 47; ++i) {
        float scur = sp[i + 1];
        float dens = softplus_f(0.5f * (sprev + scur) - 1.f);
        float delta = coarse_depth(i + 1) - coarse_depth(i);
        float alpha = 1.f - __expf(-dens * delta);
        w[i] = alpha * T + 0.01f;            // weights + 0.01
        T *= (1.f - alpha + 1e-10f);
        sprev = scur;
    }
    // blur: wp=[-inf,w,-inf]; nw_i=max(wp_i,wp_{i+1}); wb=0.5*(nw_i+nw_{i+1})+0.01
    // pdf over wb[1..45] (+1e-5 eps)
    float p[45];
    float sum = 0.f;
    #pragma unroll
    for (int i = 1; i <= 45; ++i) {
        float nwi  = fmaxf(w[i - 1], w[i]);
        float nwi1 = fmaxf(w[i], w[i + 1]);
        float wb = 0.5f * (nwi + nwi1) + 0.01f;
        float v = wb + 1e-5f;
        p[i - 1] = v;
        sum += v;
    }
    // walk cdf against monotone u=(k+0.5)/48, searchsorted-right semantics
    int k = 0;
    float cdf_lo = 0.f;
    #pragma unroll
    for (int i = 0; i < 45; ++i) {
        float cdf_hi = cdf_lo + p[i] / sum;
        float bb = zmid_c(i), ba = zmid_c(i + 1);
        float denom = cdf_hi - cdf_lo;
        if (denom < 1e-5f) denom = 1.f;
        while (k < 48) {
            float u = (k + 0.5f) / 48.f;
            if (u < cdf_hi) {
                dfine[(size_t)ray * NS + k] = bb + (u - cdf_lo) / denom * (ba - bb);
                ++k;
            } else break;
        }
        cdf_lo = cdf_hi;
    }
    while (k < 48) {  // u >= cdf[last]: inds clamps, below==above -> bins[45]
        dfine[(size_t)ray * NS + k] = zmid_c(45);
        ++k;
    }
}

// ---------------------------------------------------------------------------
// K4: merge coarse+fine (stable-sort-equivalent ranks), background MLP,
// final ray-march. One wave per ray.
// Phase A (lane=sample-pair): alpha in parallel, T via shfl prefix-product.
// Phase B (lane=channel): pure-FMA color accumulation with coalesced loads.
// ---------------------------------------------------------------------------
__global__ __launch_bounds__(256) void k_final(
    const float* __restrict__ sig_c, const float* __restrict__ rgb_c,
    const float* __restrict__ sig_f, const float* __restrict__ rgb_f,
    const float* __restrict__ dfine,
    const float* __restrict__ dirs, const float* __restrict__ z_bg,
    const float* __restrict__ bw1, const float* __restrict__ bb1,
    const float* __restrict__ bw2, const float* __restrict__ bb2,
    float* __restrict__ out_rgb, float* __restrict__ out_dep,
    float* __restrict__ out_wt)
{
    __shared__ float s_d[4][96];
    __shared__ float s_sig[4][96];
    __shared__ int   s_src[4][96];
    __shared__ float s_fine[4][48];
    __shared__ float s_w[4][96];
    __shared__ float s_g[4][96];
    __shared__ float s_h[4][64];
    __shared__ float s_zb[64];
    int lane = threadIdx.x & 63;
    int wv = threadIdx.x >> 6;
    int ray = blockIdx.x * 4 + wv;
    int bi = (blockIdx.x * 4) >> 12;      // same b for all 4 rays in block
    if (threadIdx.x < 64) s_zb[threadIdx.x] = z_bg[bi * 64 + threadIdx.x];
    if (lane < 48) s_fine[wv][lane] = dfine[(size_t)ray * NS + lane];
    __syncthreads();

    if (lane < 48) {
        // coarse element rank = lane + #{fine < coarse}
        float cd = coarse_depth(lane);
        int lo = 0, hi = 48;
        while (lo < hi) { int mid = (lo + hi) >> 1;
            if (s_fine[wv][mid] < cd) lo = mid + 1; else hi = mid; }
        int rc = lane + lo;
        s_d[wv][rc] = cd;
        s_sig[wv][rc] = sig_c[(size_t)ray * NS + lane];
        s_src[wv][rc] = lane;
        // fine element rank = lane + #{coarse <= fine}
        float f = s_fine[wv][lane];
        lo = 0; hi = 48;
        while (lo < hi) { int mid = (lo + hi) >> 1;
            if (coarse_depth(mid) <= f) lo = mid + 1; else hi = mid; }
        int rf = lane + lo;
        s_d[wv][rf] = f;
        s_sig[wv][rf] = sig_f[(size_t)ray * NS + lane];
        s_src[wv][rf] = 48 + lane;
    }
    float ddx = dirs[ray*3+0], ddy = dirs[ray*3+1], ddz = dirs[ray*3+2];
    __syncthreads();

    // ---- Phase A: per-interval alpha (2 per lane), scan T, weights ----
    float alpha0 = 0.f, alpha1 = 0.f, a0 = 1.f, a1 = 1.f;
    float dm0 = 0.f, dm1 = 0.f;
    if (lane < 48) {
        int i0 = 2 * lane, i1 = i0 + 1;
        float d0 = s_d[wv][i0], sA = s_sig[wv][i0];
        float d1 = s_d[wv][i1], sB = s_sig[wv][i1];
        {
            float dens = softplus_f(0.5f * (sA + sB) - 1.f);
            alpha0 = 1.f - __expf(-dens * (d1 - d0));
            a0 = 1.f - alpha0 + 1e-10f;
            dm0 = 0.5f * (d0 + d1);
        }
        if (i1 < 95) {
            float d2 = s_d[wv][i1 + 1], sC = s_sig[wv][i1 + 1];
            float dens = softplus_f(0.5f * (sB + sC) - 1.f);
            alpha1 = 1.f - __expf(-dens * (d2 - d1));
            a1 = 1.f - alpha1 + 1e-10f;
            dm1 = 0.5f * (d1 + d2);
        }
    }
    // inclusive prefix product of p = a0*a1 across 64 lanes
    float P = a0 * a1;
    #pragma unroll
    for (int off = 1; off < 64; off <<= 1) {
        float t = __shfl_up(P, off);
        if (lane >= off) P *= t;
    }
    float T_all = __shfl(P, 63);          // transmittance after all samples
    float E = __shfl_up(P, 1);            // exclusive
    if (lane == 0) E = 1.f;
    float w0 = alpha0 * E;
    float w1 = alpha1 * (E * a0);
    // depth / weight-total reductions
    float sw = w0 + w1;
    float sd = w0 * dm0 + w1 * dm1;
    #pragma unroll
    for (int off = 32; off; off >>= 1) {
        sw += __shfl_xor(sw, off);
        sd += __shfl_xor(sd, off);
    }
    if (lane < 48) {
        s_w[wv][2 * lane] = w0;
        s_w[wv][2 * lane + 1] = w1;       // lane47 writes w[95]=0
    }
    __syncthreads();
    // per-sample color coefficient g_i = 0.5*(w_{i-1} + w_i), w_{-1}=w_95=0
    {
        int i = lane;
        float wm = (i > 0) ? s_w[wv][i - 1] : 0.f;
        s_g[wv][i] = 0.5f * (wm + s_w[wv][i]);
        int i2 = lane + 64;
        if (lane < 32)
            s_g[wv][i2] = 0.5f * (s_w[wv][i2 - 1] + s_w[wv][i2]);
    }

    // ---- background MLP (lane j computes h_j, then lanes compute o_c) ----
    float a = bb1[lane] + ddx * bw1[lane] + ddy * bw1[64 + lane] + ddz * bw1[128 + lane];
    #pragma unroll 1
    for (int i = 0; i < 64; ++i) a += s_zb[i] * bw1[(3 + i) * 64 + lane];
    s_h[wv][lane] = softplus_f(a);
    __syncthreads();
    int c = lane & 31;
    float ob = bb2[c];
    #pragma unroll 1
    for (int j = 0; j < 64; ++j) ob += s_h[wv][j] * bw2[j * 32 + c];
    float bgc = sigmoid_f(ob);

    // ---- Phase B: color accumulation, lane = (channel, half) ----
    int h = lane >> 5;
    size_t rbase = (size_t)ray * NS * 32;
    const float* b0p = rgb_c + rbase;
    const float* b1p = rgb_f + rbase - (size_t)48 * 32;
    float acc = 0.f;
    #pragma unroll 4
    for (int i = h; i < 96; i += 2) {
        int src = s_src[wv][i];
        const float* cp = ((src < 48) ? b0p : b1p) + (size_t)src * 32;
        acc += s_g[wv][i] * cp[c];
    }
    acc += __shfl_xor(acc, 32);

    float rgbv = (acc + T_all * bgc) * 2.f - 1.f;
    float dep = sd / sw;
    if (!(dep == dep)) dep = INFINITY;          // nan_to_num(nan -> inf)
    dep = fminf(fmaxf(dep, coarse_depth(0)), coarse_depth(47));
    if (lane < 32) out_rgb[(size_t)ray * 32 + c] = rgbv;
    if (lane == 0) { out_dep[ray] = dep; out_wt[ray] = sw; }
}

// ---------------------------------------------------------------------------
extern "C" void kernel_launch(void* const* d_in, const int* in_sizes, int n_in,
                              void* d_out, int out_size, void* d_ws, size_t ws_size,
                              hipStream_t stream) {
    (void)in_sizes; (void)n_in; (void)out_size; (void)ws_size;
    const float* planes  = (const float*)d_in[0];
    const float* origins = (const float*)d_in[1];
    const float* dirs    = (const float*)d_in[2];
    const float* z_bg    = (const float*)d_in[3];
    const float* dw1     = (const float*)d_in[4];
    const float* db1     = (const float*)d_in[5];
    const float* dw2     = (const float*)d_in[6];
    const float* db2     = (const float*)d_in[7];
    const float* bw1     = (const float*)d_in[8];
    const float* bb1     = (const float*)d_in[9];
    const float* bw2     = (const float*)d_in[10];
    const float* bb2     = (const float*)d_in[11];

    // workspace layout (f32), ~311 MiB total.
    // Small buffers FIRST so planes_t has a 9MB guard region before it
    // (boundary taps with zeroed weights may read up to ~33KB before a plane).
    char* ws = (char*)d_ws;
    size_t off = 0;
    float* sig_c    = (float*)(ws + off); off += (size_t)NSAMP * 4;
    float* sig_f    = (float*)(ws + off); off += (size_t)NSAMP * 4;
    float* dfine    = (float*)(ws + off); off += (size_t)NSAMP * 4;
    float* w1t      = (float*)(ws + off); off += 64 * 32 * 4;
    float* w2p      = (float*)(ws + off); off += 64 * 36 * 4;
    float* planes_t = (float*)(ws + off); off += (size_t)NB * 3 * NH * NW * NC * 4;
    float* rgb_c    = (float*)(ws + off); off += (size_t)NSAMP * 32 * 4;
    float* rgb_f    = (float*)(ws + off); off += (size_t)NSAMP * 32 * 4;

    float* out_rgb = (float*)d_out;
    float* out_dep = out_rgb + (size_t)NRAYS * 32;
    float* out_wt  = out_dep + NRAYS;

    k_prep<<<dim3(1), dim3(256), 0, stream>>>(dw1, dw2, w1t, w2p);
    k_transpose<<<dim3(NB * 3 * 1024), dim3(256), 0, stream>>>(planes, planes_t);
    // coarse: gather feats into rgb_c, MLP in-place (feats -> rgb)
    k_gather<false><<<dim3(NSAMP / 256), dim3(256), 0, stream>>>(
        planes_t, origins, dirs, (const float*)nullptr, rgb_c);
    k_mlp<<<dim3(NSAMP / 256), dim3(256), 0, stream>>>(
        w1t, db1, w2p, db2, rgb_c, sig_c);
    k_importance<<<dim3(NRAYS / 256), dim3(256), 0, stream>>>(sig_c, dfine);
    // fine: gather feats into rgb_f, MLP in-place
    k_gather<true><<<dim3(NSAMP / 256), dim3(256), 0, stream>>>(
        planes_t, origins, dirs, dfine, rgb_f);
    k_mlp<<<dim3(NSAMP / 256), dim3(256), 0, stream>>>(
        w1t, db1, w2p, db2, rgb_f, sig_f);
    k_final<<<dim3(NRAYS / 4), dim3(256), 0, stream>>>(
        sig_c, rgb_c, sig_f, rgb_f, dfine, dirs, z_bg,
        bw1, bb1, bw2, bb2, out_rgb, out_dep, out_wt);
}

// Round 7
// 770.662 us; speedup vs baseline: 1.7587x; 1.0018x over previous
//
#include <hip/hip_runtime.h>
#include <hip/hip_bf16.h>
#include <math.h>

// Problem constants (fixed by reference)
#define NB 4
#define NR 4096
#define NC 32
#define NH 256
#define NW 256
#define NS 48
#define NRAYS (NB*NR)          // 16384
#define NSAMP (NRAYS*NS)       // 786432

__device__ __forceinline__ float coarse_depth(int i) {
    const float DELTA = 1.05f / 47.f;
    return 2.25f + i * DELTA + 0.5f * DELTA;
}
__device__ __forceinline__ float zmid_c(int i) {
    return 0.5f * (coarse_depth(i) + coarse_depth(i + 1));
}
// fast softplus: max(x,0) + log(1+exp(-|x|)) via v_exp_f32/v_log_f32
__device__ __forceinline__ float softplus_f(float x) {
    return fmaxf(x, 0.f) + __logf(1.f + __expf(-fabsf(x)));
}
__device__ __forceinline__ float sigmoid_f(float x) {
    return __frcp_rn(1.f + __expf(-x));
}

// ---------------------------------------------------------------------------
// K0: transpose planes (B,3,C,H,W) -> channel-interleaved (B*3, H*W, C)
// so one sample tap = 32 contiguous floats (128B line).
// ---------------------------------------------------------------------------
__global__ __launch_bounds__(256) void k_transpose(const float* __restrict__ in,
                                                   float* __restrict__ out) {
    __shared__ float tile[32][65];
    int bp = blockIdx.x >> 10;            // 0..11  (b*3+p)
    int t0 = (blockIdx.x & 1023) * 64;    // pixel base within 65536
    const float* src = in + (size_t)bp * NC * NH * NW;
    float* dst = out + (size_t)bp * NH * NW * NC;
    int px = threadIdx.x & 63;
    int c0 = threadIdx.x >> 6;            // 0..3
    #pragma unroll
    for (int cc = 0; cc < 32; cc += 4)
        tile[cc + c0][px] = src[(size_t)(cc + c0) * NH * NW + t0 + px];
    __syncthreads();
    int c = threadIdx.x & 31;
    int p0 = threadIdx.x >> 5;            // 0..7
    #pragma unroll
    for (int pp = 0; pp < 64; pp += 8)
        dst[(size_t)(t0 + pp + p0) * NC + c] = tile[c][pp + p0];
}

// ---------------------------------------------------------------------------
// K_prep: w1 transposed to [64][32] and w2 row-padded to [64][36] in ws,
// so the MLP kernel's uniform weight reads are contiguous (s_load-friendly).
// ---------------------------------------------------------------------------
__global__ __launch_bounds__(256) void k_prep(const float* __restrict__ w1,
                                              const float* __restrict__ w2,
                                              float* __restrict__ w1t,
                                              float* __restrict__ w2p) {
    for (int i = threadIdx.x; i < 2048; i += 256) {
        int j = i >> 5, c = i & 31;
        w1t[j * 32 + c] = w1[c * 64 + j];
    }
    for (int i = threadIdx.x; i < 64 * 36; i += 256) {
        int j = i / 36, kx = i - j * 36;
        w2p[i] = (kx < 33) ? w2[j * 33 + kx] : 0.f;
    }
}

// ---------------------------------------------------------------------------
// K1a/K3a: tri-plane gather. NO LDS -> occupancy is VGPR-bound (~7-8 w/SIMD)
// so the scattered L2/L3 tap latency is hidden by TLP.
// Phase 1 (lane=sample): address math + per-corner-zeroed weights, once.
// Phase 2 (half-wave, lane=channel): meta via __shfl, coalesced taps,
// features written straight to global (aliases the rgb buffer).
// ---------------------------------------------------------------------------
template<bool FINE>
__global__ __launch_bounds__(256) void k_gather(
    const float* __restrict__ planes_t,
    const float* __restrict__ origins,
    const float* __restrict__ dirs,
    const float* __restrict__ dfine,       // null for coarse
    float* __restrict__ feats_out)         // [NSAMP][32]
{
    int lane  = threadIdx.x & 63;
    int wbase = threadIdx.x & 192;        // (tid>>6)*64: wave's sample base
    int s0    = blockIdx.x * 256 + wbase;

    // ---- phase 1: meta for OWN sample (registers) ----
    int s   = s0 + lane;
    int ray = s / NS;
    int kk  = s - ray * NS;
    float t = FINE ? dfine[s] : coarse_depth(kk);
    float ox = origins[ray*3+0], oy = origins[ray*3+1], oz = origins[ray*3+2];
    float ddx = dirs[ray*3+0],   ddy = dirs[ray*3+1],   ddz = dirs[ray*3+2];
    float cx = 2.f * (ox + t * ddx);
    float cy = 2.f * (oy + t * ddy);
    float cz = 2.f * (oz + t * ddz);
    int bi = ray >> 12;                   // /NR
    int   m_base[3];
    float m_q[3][4];
    #pragma unroll
    for (int p = 0; p < 3; ++p) {
        // plane0:(cx,cy)  plane1:(cx,cz)  plane2:(cz,cx)
        float gx = (p == 2) ? cz : cx;
        float gy = (p == 0) ? cy : ((p == 1) ? cz : cx);
        float fx = (gx + 1.f) * 128.f - 0.5f;
        float fy = (gy + 1.f) * 128.f - 0.5f;
        float x0f = floorf(fx), y0f = floorf(fy);
        float wx = fx - x0f, wy = fy - y0f;
        int x0 = (int)x0f, y0 = (int)y0f;
        if (x0 >= -1 && x0 <= 255 && y0 >= -1 && y0 <= 255) {
            float wxm = 1.f - wx, wym = 1.f - wy;
            float q00 = wxm*wym, q10 = wx*wym, q01 = wxm*wy, q11 = wx*wy;
            // per-corner validity folded into weights (== reference mask)
            if (!(x0 >= 0   && y0 >= 0))   q00 = 0.f;
            if (!(x0 <= 254 && y0 >= 0))   q10 = 0.f;
            if (!(x0 >= 0   && y0 <= 254)) q01 = 0.f;
            if (!(x0 <= 254 && y0 <= 254)) q11 = 0.f;
            // NOTE: base may be up to 8224 elems before the plane (x0=y0=-1),
            // those reads land in the sigma/dfine buffers that precede
            // planes_t in ws — in-bounds, finite, and multiplied by 0.
            m_base[p] = (bi*3 + p) * (NH*NW*NC) + (y0*NW + x0)*NC;
            m_q[p][0] = q00; m_q[p][1] = q10; m_q[p][2] = q01; m_q[p][3] = q11;
        } else {
            m_base[p] = -1;               // fully out: skip sentinel
            m_q[p][0] = m_q[p][1] = m_q[p][2] = m_q[p][3] = 0.f;
        }
    }

    // ---- phase 2: gather (2 samples/iter, half-wave lane=channel) ----
    int ch   = lane & 31;
    int half = lane >> 5;
    #pragma unroll 1
    for (int i = 0; i < 64; i += 2) {
        int src = i + half;               // meta source lane
        float acc = 0.f;
        #pragma unroll
        for (int p = 0; p < 3; ++p) {
            int   bse = __shfl(m_base[p], src);
            float q00 = __shfl(m_q[p][0], src);
            float q10 = __shfl(m_q[p][1], src);
            float q01 = __shfl(m_q[p][2], src);
            float q11 = __shfl(m_q[p][3], src);
            if (bse >= 0) {
                const float* ptr = planes_t + (size_t)bse + ch;
                acc += q00 * ptr[0]    + q10 * ptr[32]
                     + q01 * ptr[8192] + q11 * ptr[8224];
            }
        }
        feats_out[(size_t)(s0 + i + half) * 32 + ch] = acc * (1.f / 3.f);
    }
}

// ---------------------------------------------------------------------------
// K1b/K3b: decode MLP, thread-per-sample, IN-PLACE (feats -> rgb).
// x[32] read as 8x float4; weights via uniform const-restrict reads
// (scalar-promoted to s_load -> SGPR operands).
// __launch_bounds__(256, 4): 4 waves/EU -> ~128-VGPR budget. Without the
// second arg the allocator targeted ~44 VGPR and SPILLED x[]/o[] to scratch
// (R6 counters: VGPR=44 < 65 live floats, WRITE_SIZE 156MB vs 103MB real
// output, dur 4x the VALU floor).
// ---------------------------------------------------------------------------
__global__ __launch_bounds__(256, 4) void k_mlp(
    const float* __restrict__ w1t,   // [64][32]
    const float* __restrict__ b1,
    const float* __restrict__ w2p,   // [64][36] (rows padded)
    const float* __restrict__ b2,
    float* __restrict__ rgb_io,      // in: feats, out: rgb
    float* __restrict__ sig_out)
{
    int s = blockIdx.x * 256 + threadIdx.x;
    float* base = rgb_io + (size_t)s * 32;
    float x[32];
    #pragma unroll
    for (int i = 0; i < 8; ++i) {
        float4 v = ((const float4*)base)[i];
        x[4*i+0] = v.x; x[4*i+1] = v.y; x[4*i+2] = v.z; x[4*i+3] = v.w;
    }
    float o[33];
    #pragma unroll
    for (int k2 = 0; k2 < 33; ++k2) o[k2] = b2[k2];
    #pragma unroll 4
    for (int j = 0; j < 64; ++j) {
        float a = b1[j];
        #pragma unroll
        for (int c = 0; c < 32; ++c) a += x[c] * w1t[j * 32 + c];
        float h = softplus_f(a);
        #pragma unroll
        for (int k2 = 0; k2 < 33; ++k2) o[k2] += h * w2p[j * 36 + k2];
    }
    sig_out[s] = o[0];
    #pragma unroll
    for (int i = 0; i < 8; ++i) {
        float4 r;
        r.x = sigmoid_f(o[1 + 4*i + 0]) * 1.002f - 0.001f;
        r.y = sigmoid_f(o[1 + 4*i + 1]) * 1.002f - 0.001f;
        r.z = sigmoid_f(o[1 + 4*i + 2]) * 1.002f - 0.001f;
        r.w = sigmoid_f(o[1 + 4*i + 3]) * 1.002f - 0.001f;
        ((float4*)base)[i] = r;
    }
}

// ---------------------------------------------------------------------------
// K2: coarse ray-march -> weights -> blur -> PDF -> 48 importance depths.
// Thread-per-ray, fully unrolled register arrays.
// ---------------------------------------------------------------------------
__global__ __launch_bounds__(256) void k_importance(const float* __restrict__ sig,
                                                    float* __restrict__ dfine) {
    int ray = blockIdx.x * 256 + threadIdx.x;
    const float* sp = sig + (size_t)ray * NS;
    float w[47];
    float T = 1.f;
    float sprev = sp[0];
    #pragma unroll
    for (int i = 0; i < 47; ++i) {
        float scur = sp[i + 1];
        float dens = softplus_f(0.5f * (sprev + scur) - 1.f);
        float delta = coarse_depth(i + 1) - coarse_depth(i);
        float alpha = 1.f - __expf(-dens * delta);
        w[i] = alpha * T + 0.01f;            // weights + 0.01
        T *= (1.f - alpha + 1e-10f);
        sprev = scur;
    }
    // blur: wp=[-inf,w,-inf]; nw_i=max(wp_i,wp_{i+1}); wb=0.5*(nw_i+nw_{i+1})+0.01
    // pdf over wb[1..45] (+1e-5 eps)
    float p[45];
    float sum = 0.f;
    #pragma unroll
    for (int i = 1; i <= 45; ++i) {
        float nwi  = fmaxf(w[i - 1], w[i]);
        float nwi1 = fmaxf(w[i], w[i + 1]);
        float wb = 0.5f * (nwi + nwi1) + 0.01f;
        float v = wb + 1e-5f;
        p[i - 1] = v;
        sum += v;
    }
    // walk cdf against monotone u=(k+0.5)/48, searchsorted-right semantics
    int k = 0;
    float cdf_lo = 0.f;
    #pragma unroll
    for (int i = 0; i < 45; ++i) {
        float cdf_hi = cdf_lo + p[i] / sum;
        float bb = zmid_c(i), ba = zmid_c(i + 1);
        float denom = cdf_hi - cdf_lo;
        if (denom < 1e-5f) denom = 1.f;
        while (k < 48) {
            float u = (k + 0.5f) / 48.f;
            if (u < cdf_hi) {
                dfine[(size_t)ray * NS + k] = bb + (u - cdf_lo) / denom * (ba - bb);
                ++k;
            } else break;
        }
        cdf_lo = cdf_hi;
    }
    while (k < 48) {  // u >= cdf[last]: inds clamps, below==above -> bins[45]
        dfine[(size_t)ray * NS + k] = zmid_c(45);
        ++k;
    }
}

// ---------------------------------------------------------------------------
// K4: merge coarse+fine (stable-sort-equivalent ranks), background MLP,
// final ray-march. One wave per ray.
// Phase A (lane=sample-pair): alpha in parallel, T via shfl prefix-product.
// Phase B (lane=channel): pure-FMA color accumulation with coalesced loads.
// ---------------------------------------------------------------------------
__global__ __launch_bounds__(256) void k_final(
    const float* __restrict__ sig_c, const float* __restrict__ rgb_c,
    const float* __restrict__ sig_f, const float* __restrict__ rgb_f,
    const float* __restrict__ dfine,
    const float* __restrict__ dirs, const float* __restrict__ z_bg,
    const float* __restrict__ bw1, const float* __restrict__ bb1,
    const float* __restrict__ bw2, const float* __restrict__ bb2,
    float* __restrict__ out_rgb, float* __restrict__ out_dep,
    float* __restrict__ out_wt)
{
    __shared__ float s_d[4][96];
    __shared__ float s_sig[4][96];
    __shared__ int   s_src[4][96];
    __shared__ float s_fine[4][48];
    __shared__ float s_w[4][96];
    __shared__ float s_g[4][96];
    __shared__ float s_h[4][64];
    __shared__ float s_zb[64];
    int lane = threadIdx.x & 63;
    int wv = threadIdx.x >> 6;
    int ray = blockIdx.x * 4 + wv;
    int bi = (blockIdx.x * 4) >> 12;      // same b for all 4 rays in block
    if (threadIdx.x < 64) s_zb[threadIdx.x] = z_bg[bi * 64 + threadIdx.x];
    if (lane < 48) s_fine[wv][lane] = dfine[(size_t)ray * NS + lane];
    __syncthreads();

    if (lane < 48) {
        // coarse element rank = lane + #{fine < coarse}
        float cd = coarse_depth(lane);
        int lo = 0, hi = 48;
        while (lo < hi) { int mid = (lo + hi) >> 1;
            if (s_fine[wv][mid] < cd) lo = mid + 1; else hi = mid; }
        int rc = lane + lo;
        s_d[wv][rc] = cd;
        s_sig[wv][rc] = sig_c[(size_t)ray * NS + lane];
        s_src[wv][rc] = lane;
        // fine element rank = lane + #{coarse <= fine}
        float f = s_fine[wv][lane];
        lo = 0; hi = 48;
        while (lo < hi) { int mid = (lo + hi) >> 1;
            if (coarse_depth(mid) <= f) lo = mid + 1; else hi = mid; }
        int rf = lane + lo;
        s_d[wv][rf] = f;
        s_sig[wv][rf] = sig_f[(size_t)ray * NS + lane];
        s_src[wv][rf] = 48 + lane;
    }
    float ddx = dirs[ray*3+0], ddy = dirs[ray*3+1], ddz = dirs[ray*3+2];
    __syncthreads();

    // ---- Phase A: per-interval alpha (2 per lane), scan T, weights ----
    float alpha0 = 0.f, alpha1 = 0.f, a0 = 1.f, a1 = 1.f;
    float dm0 = 0.f, dm1 = 0.f;
    if (lane < 48) {
        int i0 = 2 * lane, i1 = i0 + 1;
        float d0 = s_d[wv][i0], sA = s_sig[wv][i0];
        float d1 = s_d[wv][i1], sB = s_sig[wv][i1];
        {
            float dens = softplus_f(0.5f * (sA + sB) - 1.f);
            alpha0 = 1.f - __expf(-dens * (d1 - d0));
            a0 = 1.f - alpha0 + 1e-10f;
            dm0 = 0.5f * (d0 + d1);
        }
        if (i1 < 95) {
            float d2 = s_d[wv][i1 + 1], sC = s_sig[wv][i1 + 1];
            float dens = softplus_f(0.5f * (sB + sC) - 1.f);
            alpha1 = 1.f - __expf(-dens * (d2 - d1));
            a1 = 1.f - alpha1 + 1e-10f;
            dm1 = 0.5f * (d1 + d2);
        }
    }
    // inclusive prefix product of p = a0*a1 across 64 lanes
    float P = a0 * a1;
    #pragma unroll
    for (int off = 1; off < 64; off <<= 1) {
        float t = __shfl_up(P, off);
        if (lane >= off) P *= t;
    }
    float T_all = __shfl(P, 63);          // transmittance after all samples
    float E = __shfl_up(P, 1);            // exclusive
    if (lane == 0) E = 1.f;
    float w0 = alpha0 * E;
    float w1 = alpha1 * (E * a0);
    // depth / weight-total reductions
    float sw = w0 + w1;
    float sd = w0 * dm0 + w1 * dm1;
    #pragma unroll
    for (int off = 32; off; off >>= 1) {
        sw += __shfl_xor(sw, off);
        sd += __shfl_xor(sd, off);
    }
    if (lane < 48) {
        s_w[wv][2 * lane] = w0;
        s_w[wv][2 * lane + 1] = w1;       // lane47 writes w[95]=0
    }
    __syncthreads();
    // per-sample color coefficient g_i = 0.5*(w_{i-1} + w_i), w_{-1}=w_95=0
    {
        int i = lane;
        float wm = (i > 0) ? s_w[wv][i - 1] : 0.f;
        s_g[wv][i] = 0.5f * (wm + s_w[wv][i]);
        int i2 = lane + 64;
        if (lane < 32)
            s_g[wv][i2] = 0.5f * (s_w[wv][i2 - 1] + s_w[wv][i2]);
    }

    // ---- background MLP (lane j computes h_j, then lanes compute o_c) ----
    float a = bb1[lane] + ddx * bw1[lane] + ddy * bw1[64 + lane] + ddz * bw1[128 + lane];
    #pragma unroll 1
    for (int i = 0; i < 64; ++i) a += s_zb[i] * bw1[(3 + i) * 64 + lane];
    s_h[wv][lane] = softplus_f(a);
    __syncthreads();
    int c = lane & 31;
    float ob = bb2[c];
    #pragma unroll 1
    for (int j = 0; j < 64; ++j) ob += s_h[wv][j] * bw2[j * 32 + c];
    float bgc = sigmoid_f(ob);

    // ---- Phase B: color accumulation, lane = (channel, half) ----
    int h = lane >> 5;
    size_t rbase = (size_t)ray * NS * 32;
    const float* b0p = rgb_c + rbase;
    const float* b1p = rgb_f + rbase - (size_t)48 * 32;
    float acc = 0.f;
    #pragma unroll 4
    for (int i = h; i < 96; i += 2) {
        int src = s_src[wv][i];
        const float* cp = ((src < 48) ? b0p : b1p) + (size_t)src * 32;
        acc += s_g[wv][i] * cp[c];
    }
    acc += __shfl_xor(acc, 32);

    float rgbv = (acc + T_all * bgc) * 2.f - 1.f;
    float dep = sd / sw;
    if (!(dep == dep)) dep = INFINITY;          // nan_to_num(nan -> inf)
    dep = fminf(fmaxf(dep, coarse_depth(0)), coarse_depth(47));
    if (lane < 32) out_rgb[(size_t)ray * 32 + c] = rgbv;
    if (lane == 0) { out_dep[ray] = dep; out_wt[ray] = sw; }
}

// ---------------------------------------------------------------------------
extern "C" void kernel_launch(void* const* d_in, const int* in_sizes, int n_in,
                              void* d_out, int out_size, void* d_ws, size_t ws_size,
                              hipStream_t stream) {
    (void)in_sizes; (void)n_in; (void)out_size; (void)ws_size;
    const float* planes  = (const float*)d_in[0];
    const float* origins = (const float*)d_in[1];
    const float* dirs    = (const float*)d_in[2];
    const float* z_bg    = (const float*)d_in[3];
    const float* dw1     = (const float*)d_in[4];
    const float* db1     = (const float*)d_in[5];
    const float* dw2     = (const float*)d_in[6];
    const float* db2     = (const float*)d_in[7];
    const float* bw1     = (const float*)d_in[8];
    const float* bb1     = (const float*)d_in[9];
    const float* bw2     = (const float*)d_in[10];
    const float* bb2     = (const float*)d_in[11];

    // workspace layout (f32), ~311 MiB total.
    // Small buffers FIRST so planes_t has a 9MB guard region before it
    // (boundary taps with zeroed weights may read up to ~33KB before a plane).
    char* ws = (char*)d_ws;
    size_t off = 0;
    float* sig_c    = (float*)(ws + off); off += (size_t)NSAMP * 4;
    float* sig_f    = (float*)(ws + off); off += (size_t)NSAMP * 4;
    float* dfine    = (float*)(ws + off); off += (size_t)NSAMP * 4;
    float* w1t      = (float*)(ws + off); off += 64 * 32 * 4;
    float* w2p      = (float*)(ws + off); off += 64 * 36 * 4;
    float* planes_t = (float*)(ws + off); off += (size_t)NB * 3 * NH * NW * NC * 4;
    float* rgb_c    = (float*)(ws + off); off += (size_t)NSAMP * 32 * 4;
    float* rgb_f    = (float*)(ws + off); off += (size_t)NSAMP * 32 * 4;

    float* out_rgb = (float*)d_out;
    float* out_dep = out_rgb + (size_t)NRAYS * 32;
    float* out_wt  = out_dep + NRAYS;

    k_prep<<<dim3(1), dim3(256), 0, stream>>>(dw1, dw2, w1t, w2p);
    k_transpose<<<dim3(NB * 3 * 1024), dim3(256), 0, stream>>>(planes, planes_t);
    // coarse: gather feats into rgb_c, MLP in-place (feats -> rgb)
    k_gather<false><<<dim3(NSAMP / 256), dim3(256), 0, stream>>>(
        planes_t, origins, dirs, (const float*)nullptr, rgb_c);
    k_mlp<<<dim3(NSAMP / 256), dim3(256), 0, stream>>>(
        w1t, db1, w2p, db2, rgb_c, sig_c);
    k_importance<<<dim3(NRAYS / 256), dim3(256), 0, stream>>>(sig_c, dfine);
    // fine: gather feats into rgb_f, MLP in-place
    k_gather<true><<<dim3(NSAMP / 256), dim3(256), 0, stream>>>(
        planes_t, origins, dirs, dfine, rgb_f);
    k_mlp<<<dim3(NSAMP / 256), dim3(256), 0, stream>>>(
        w1t, db1, w2p, db2, rgb_f, sig_f);
    k_final<<<dim3(NRAYS / 4), dim3(256), 0, stream>>>(
        sig_c, rgb_c, sig_f, rgb_f, dfine, dirs, z_bg,
        bw1, bb1, bw2, bb2, out_rgb, out_dep, out_wt);
}